// Round 3
// baseline (126.884 us; speedup 1.0000x reference)
//
#include <hip/hip_runtime.h>

// B=16, 12 in-ch, 128x128 imgs; conv1->64ch +pool -> 64x64; conv2->128ch (+PE);
// roi max -> out (16,32,128) f32.
//
// Pipeline: k0 (roi bitmask) ; k0b (images -> bf16 [b][row][col][ci16] imgT) ;
// kw/kw1 (weights -> bf16 MFMA-fragment order) ; k1_mfma (conv1+relu+pool ->
// bf16 pooledT [b][ph][pw][co]) ; k2_mfma (conv2+relu+PE -> f32 x2) ; k3 (roi max).

typedef __attribute__((ext_vector_type(8))) short short8;   // MFMA bf16 A/B frag
typedef __attribute__((ext_vector_type(4))) float f32x4;    // MFMA C/D frag
typedef __attribute__((ext_vector_type(4))) unsigned short us4;
typedef unsigned short u16;

__device__ __forceinline__ u16 f2bf(float f) {  // RNE f32 -> bf16 bits
  unsigned u = __builtin_bit_cast(unsigned, f);
  return (u16)((u + 0x7fffu + ((u >> 16) & 1u)) >> 16);
}

namespace {

// ---------------- k0: rois[:,:,::2,::2] -> per-position 32-bit object mask ----
__global__ __launch_bounds__(256) void k0_rmask(const unsigned* __restrict__ rois,
                                                unsigned* __restrict__ rmask) {
  const int lane = threadIdx.x & 63;
  unsigned ok = 1u;
#pragma unroll
  for (int i = 0; i < 4; ++i) {
    unsigned v = rois[lane * 4 + i];
    ok &= ((v <= 1u) || (v == 0x3f800000u)) ? 1u : 0u;
  }
  const bool isWord = (__all((int)ok) != 0);  // 4-byte elements
  const unsigned char* roisB = (const unsigned char*)rois;

  const int pos = blockIdx.x * 256 + threadIdx.x;
  const int b = pos >> 12;
  const int p = pos & 4095;
  const int h = (p >> 6) << 1;
  const int w = (p & 63) << 1;
  const size_t base = (size_t)b * 32 * 16384 + (size_t)h * 128 + (size_t)w;
  unsigned m = 0;
#pragma unroll
  for (int o = 0; o < 32; ++o) {
    const size_t idx = base + (size_t)o * 16384;
    unsigned bit = isWord ? (unsigned)(rois[idx] != 0u) : (unsigned)(roisB[idx] != 0);
    m |= bit << o;
  }
  rmask[pos] = m;
}

// ---------------- k0b: images f32 [b][12][128][128] -> bf16 imgT [b][row][col][16] (ci pad->0)
__global__ __launch_bounds__(256) void k0b_imgT(const float* __restrict__ img,
                                                u16* __restrict__ imgT) {
  __shared__ alignas(16) u16 ST[2048];  // [col 0..127][cip 0..15]
  const int row = blockIdx.x, b = blockIdx.y;
  const int t = threadIdx.x;
#pragma unroll
  for (int i = 0; i < 2; ++i) {  // zero pads cip 12..15
    const int e = i * 256 + t;   // 0..511
    ST[(e >> 2) * 16 + 12 + (e & 3)] = 0;
  }
#pragma unroll
  for (int i = 0; i < 6; ++i) {  // 12 ci x 128 col
    const int e = i * 256 + t;   // 0..1535
    const int ci = e >> 7, col = e & 127;
    const float v = img[(((size_t)(b * 12 + ci)) << 14) + row * 128 + col];
    ST[col * 16 + ci] = f2bf(v);
  }
  __syncthreads();
  us4* dst = (us4*)(imgT + (((size_t)(b * 128 + row)) << 11));
#pragma unroll
  for (int i = 0; i < 2; ++i) {
    const int q = i * 256 + t;  // 0..511 us4 chunks
    dst[q] = *(const us4*)&ST[q * 4];
  }
}

// ---------------- kw: w2 f32 [co][64][3][3] -> bf16 A-fragments, K-order k=32ks+g*8+j,
// k -> (rc = k>>6, ci = k&63), src = w2[co*576 + ci*9 + rc]. idx=((cot*18+ks)*64+lane)*8+j
__global__ __launch_bounds__(256) void kw_prep(const float* __restrict__ w2,
                                               u16* __restrict__ Aw) {
  const int idx = blockIdx.x * 256 + threadIdx.x;  // 0..73727
  const int j = idx & 7;
  const int lane = (idx >> 3) & 63;
  const int t3 = idx >> 9;
  const int ks = t3 % 18, cot = t3 / 18;
  const int m = lane & 15, g = lane >> 4;
  const int co = cot * 16 + m;
  const int k = ks * 32 + g * 8 + j;
  const int rc = k >> 6, ci = k & 63;
  Aw[idx] = f2bf(w2[co * 576 + ci * 9 + rc]);
}

// ---------------- kw1: w1 f32 [co][12][3][3] -> bf16 A-frags, K padded 108->160.
// k=32ks+g*8+j -> (rc=k>>4, cip=k&15); pad (rc>=9 || cip>=12) -> 0.
__global__ __launch_bounds__(256) void kw1_prep(const float* __restrict__ w1,
                                                u16* __restrict__ Aw1) {
  const int idx = blockIdx.x * 256 + threadIdx.x;  // 0..10239
  const int j = idx & 7;
  const int lane = (idx >> 3) & 63;
  const int t3 = idx >> 9;           // cot*5 + ks
  const int ks = t3 % 5, cot = t3 / 5;
  const int m = lane & 15, g = lane >> 4;
  const int co = cot * 16 + m;
  const int k = ks * 32 + g * 8 + j;
  const int rc = k >> 4, cip = k & 15;
  const float v = (rc < 9 && cip < 12) ? w1[co * 108 + cip * 9 + rc] : 0.f;
  Aw1[idx] = f2bf(v);
}

// ---------------- k1: conv1 (MFMA) + bias + relu + pool -> pooledT bf16 [b][ph][pw][co]
// block: (h2 = pooled row, b). Stages img rows 2h2-1..2h2+2 as [4][128 col][16 cip].
// wave wv: co-tiles {2(wv&1), +1} x cols [ (wv>>1)*64, +64 ) x conv rows {2h2, 2h2+1}.
__global__ __launch_bounds__(256) void k1_mfma(const u16* __restrict__ imgT,
                                               const u16* __restrict__ Aw1,
                                               const float* __restrict__ b1,
                                               u16* __restrict__ pooledT) {
  __shared__ alignas(16) u16 SIMG[8192];     // 16 KB
  __shared__ alignas(16) u16 PT[64 * 68];    // pooled [pw][co], pad-68 stride
  const int h2 = blockIdx.x, b = blockIdx.y;
  const int t = threadIdx.x, wv = t >> 6, l = t & 63;

#pragma unroll
  for (int i = 0; i < 4; ++i) {  // stage 4 rows x 4KB
    const int q = i * 256 + t;   // 16B chunk 0..1023
    const int sr = q >> 8, off = q & 255;
    const int irow = 2 * h2 - 1 + sr;
    short8 v = {0, 0, 0, 0, 0, 0, 0, 0};
    if ((unsigned)irow < 128u)
      v = *(const short8*)(imgT + (((size_t)(b * 128 + irow)) << 11) + off * 8);
    *(short8*)(SIMG + q * 8) = v;
  }
  __syncthreads();

  const int m16 = l & 15, g = l >> 4;
  const int colhalf = wv >> 1, cotbase = (wv & 1) * 2;
  f32x4 acc[2][8];
#pragma unroll
  for (int ct = 0; ct < 2; ++ct)
#pragma unroll
    for (int pt = 0; pt < 8; ++pt) acc[ct][pt] = (f32x4){0.f, 0.f, 0.f, 0.f};

  const u16* awb = Aw1 + (size_t)l * 8;
  const int cipb = (g & 1) * 16;  // byte offset of cip0 within 32B col-slot

#pragma unroll
  for (int ks = 0; ks < 5; ++ks) {
    short8 a0 = *(const short8*)(awb + (cotbase * 5 + ks) * 512);
    short8 a1 = *(const short8*)(awb + ((cotbase + 1) * 5 + ks) * 512);
    const bool pad = (ks == 4) && (g >= 2);  // k in [144,160): zero slots
    int rc = pad ? 0 : (2 * ks + (g >> 1));  // 0..8
    const int rr = (rc * 11) >> 5;           // rc/3
    const int cc = rc - rr * 3;              // rc%3
#pragma unroll
    for (int pt = 0; pt < 8; ++pt) {
      const int r01 = pt >> 2, ct2 = pt & 3;
      const int icol = colhalf * 64 + ct2 * 16 + m16 - 1 + cc;  // -1..128
      const bool ok = ((unsigned)icol < 128u) && !pad;
      const int ic = ok ? icol : 0;
      const int sr = r01 + rr;  // 0..3 (pad forces rr=0)
      short8 bv = *(const short8*)((const char*)SIMG + sr * 4096 + ic * 32 + cipb);
      if (!ok) bv = (short8){0, 0, 0, 0, 0, 0, 0, 0};
      acc[0][pt] = __builtin_amdgcn_mfma_f32_16x16x32_bf16(a0, bv, acc[0][pt], 0, 0, 0);
      acc[1][pt] = __builtin_amdgcn_mfma_f32_16x16x32_bf16(a1, bv, acc[1][pt], 0, 0, 0);
    }
  }

  // relu + 2x2 pool (rows in-lane, col pairs via shfl_xor) -> PT[pw][co]
#pragma unroll
  for (int ct = 0; ct < 2; ++ct) {
    const int cot = cotbase + ct;
#pragma unroll
    for (int r = 0; r < 4; ++r) {
      const int co = cot * 16 + g * 4 + r;
      const float bias = b1[co];
#pragma unroll
      for (int ct2 = 0; ct2 < 4; ++ct2) {
        float v0 = fmaxf(acc[ct][ct2][r] + bias, 0.f);
        float v1 = fmaxf(acc[ct][4 + ct2][r] + bias, 0.f);
        float vv = fmaxf(v0, v1);
        vv = fmaxf(vv, __shfl_xor(vv, 1, 64));
        if (!(m16 & 1)) {
          const int pw = colhalf * 32 + ct2 * 8 + (m16 >> 1);
          PT[pw * 68 + co] = f2bf(vv);
        }
      }
    }
  }
  __syncthreads();
  u16* dst = pooledT + (((size_t)(b * 64 + h2)) << 12);
#pragma unroll
  for (int i = 0; i < 4; ++i) {
    const int e = (i * 256 + t) * 4;
    const int pw = e >> 6, co = e & 63;
    *(us4*)(dst + e) = *(const us4*)&PT[pw * 68 + co];
  }
}

// ---------------- k2: conv2 (MFMA) + bias + relu + PE -> x2 f32 [b][co][h][w]
// block: (h, b). Stages pooledT rows h-1..h+1 as [3][64 col][64 ci], XOR-swizzled.
// wave wv: co-tiles {2wv, 2wv+1} x all 64 cols (4 pos-tiles). K = 576 = 18 ksteps.
__global__ __launch_bounds__(256) void k2_mfma(const u16* __restrict__ pooledT,
                                               const u16* __restrict__ Aw,
                                               const float* __restrict__ b2,
                                               const float* __restrict__ dw,
                                               const float* __restrict__ db,
                                               float* __restrict__ x2) {
  __shared__ alignas(16) short8 SIN8[1536];  // 24 KB
  char* SB = (char*)SIN8;
  const int h = blockIdx.x, b = blockIdx.y;
  const int t = threadIdx.x, wv = t >> 6, l = t & 63;

#pragma unroll
  for (int i = 0; i < 6; ++i) {  // 24 chunks x 1KB
    const int chunk = i * 4 + wv;
    const int row = chunk >> 3;
    const int hin = h - 1 + row;
    short8 v = {0, 0, 0, 0, 0, 0, 0, 0};
    if ((unsigned)hin < 64u)
      v = *(const short8*)(pooledT + (((size_t)(b * 64 + hin)) << 12) +
                           ((chunk & 7) << 9) + l * 8);
    const int lin = chunk * 1024 + l * 16;
    *(short8*)(SB + (lin ^ (((lin >> 7) & 7) << 4))) = v;  // T2 XOR swizzle
  }
  __syncthreads();

  const int m16 = l & 15, g = l >> 4;
  const int kbyte = g * 16;
  f32x4 acc[2][4];
#pragma unroll
  for (int ct = 0; ct < 2; ++ct)
#pragma unroll
    for (int n = 0; n < 4; ++n) acc[ct][n] = (f32x4){0.f, 0.f, 0.f, 0.f};

  const u16* aw0 = Aw + (size_t)wv * 36 * 512 + l * 8;  // cot = 2wv

#pragma unroll
  for (int ks = 0; ks < 18; ++ks) {
    const int rc = ks >> 1, r = rc / 3, c = rc % 3;  // compile-time
    const int koff = r * 8192 + (ks & 1) * 64 + kbyte;
    short8 a0 = *(const short8*)(aw0 + ks * 512);
    short8 a1 = *(const short8*)(aw0 + (18 + ks) * 512);
    const int d = m16 + c - 1;  // -1..16
#pragma unroll
    for (int n = 0; n < 4; ++n) {
      const int icol = n * 16 + d;
      const bool ok = (unsigned)icol < 64u;
      const int ic = ok ? icol : (icol < 0 ? 0 : 63);
      int addr = koff + ic * 128;
      addr ^= (ic & 7) << 4;  // matching read-side swizzle
      short8 bv = *(const short8*)(SB + addr);
      if (!ok) bv = (short8){0, 0, 0, 0, 0, 0, 0, 0};
      acc[0][n] = __builtin_amdgcn_mfma_f32_16x16x32_bf16(a0, bv, acc[0][n], 0, 0, 0);
      acc[1][n] = __builtin_amdgcn_mfma_f32_16x16x32_bf16(a1, bv, acc[1][n], 0, 0, 0);
    }
  }

  // epilogue: relu(acc + b2) + pe ; pe = gy*(W0-W2) + gx*(W1-W3) + W2+W3+db
  const float inv63 = 1.f / 63.f;
  const float gy = (float)h * inv63;
#pragma unroll
  for (int ct = 0; ct < 2; ++ct) {
    const int cot = wv * 2 + ct;
#pragma unroll
    for (int r = 0; r < 4; ++r) {
      const int co = cot * 16 + g * 4 + r;
      const float bias = b2[co];
      const float W0 = dw[co * 4 + 0], W1 = dw[co * 4 + 1];
      const float W2 = dw[co * 4 + 2], W3 = dw[co * 4 + 3];
      const float pe0 = gy * (W0 - W2) + W2 + W3 + db[co];
      const float s13 = W1 - W3;
      float* orow = x2 + (((size_t)(b * 128 + co)) << 12) + h * 64;
#pragma unroll
      for (int n = 0; n < 4; ++n) {
        const int w = n * 16 + m16;
        orow[w] = fmaxf(acc[ct][n][r] + bias, 0.f) + pe0 + (float)w * inv63 * s13;
      }
    }
  }
}

// ---------------- k3: out[b,o,c] = max over pos of x2[b,c,pos] * r[b,o,pos] ---
// v2: block = (c-quad, b), 512 blocks x 4 waves. Thread scans 16 pos for 4
// c-planes; mask decode (2 ops) shared across the 4 planes (2 ops each).
// amask = sign-replicated bit o -> sel = and(x, amask) = mask ? x : +0.0,
// identical to reference's x*r. 128 f32 accums/thread kept in VGPRs via
// __launch_bounds__(256,2) (~140 VGPR -> no AGPR ping-pong, no spill).
__global__ __launch_bounds__(256, 2) void k3_roi(const float* __restrict__ x2,
                                                 const unsigned* __restrict__ rmask,
                                                 float* __restrict__ out) {
  __shared__ float red[4][4][32];  // [wave][cj][o]
  const int cq = blockIdx.x, b = blockIdx.y;
  const int t = threadIdx.x, wv = t >> 6;
  const float* p0 = x2 + ((size_t)(b * 128 + cq * 4)) * 4096;
  const unsigned* mb = rmask + b * 4096;

  float m[4][32];
#pragma unroll
  for (int j = 0; j < 4; ++j)
#pragma unroll
    for (int o = 0; o < 32; ++o) m[j][o] = -3.4e38f;

  for (int k = 0; k < 16; ++k) {
    const int pos = k * 256 + t;
    const unsigned mk = mb[pos];
    float xv[4];
#pragma unroll
    for (int j = 0; j < 4; ++j) xv[j] = p0[j * 4096 + pos];
#pragma unroll
    for (int o = 0; o < 32; ++o) {
      const unsigned am = (unsigned)((int)(mk << (31 - o)) >> 31);  // bit o -> 0/~0
#pragma unroll
      for (int j = 0; j < 4; ++j) {
        const float sel = __builtin_bit_cast(
            float, __builtin_bit_cast(unsigned, xv[j]) & am);
        m[j][o] = fmaxf(m[j][o], sel);
      }
    }
  }

  // in-wave butterfly per accumulator, then 4-way cross-wave merge via LDS
#pragma unroll
  for (int j = 0; j < 4; ++j)
#pragma unroll
    for (int o = 0; o < 32; ++o) {
#pragma unroll
      for (int s = 32; s >= 1; s >>= 1)
        m[j][o] = fmaxf(m[j][o], __shfl_xor(m[j][o], s, 64));
    }
  const int lane = t & 63;
  if (lane < 32) {
#pragma unroll
    for (int j = 0; j < 4; ++j) red[wv][j][lane] = m[j][lane];
  }
  __syncthreads();
  if (t < 128) {
    const int j = t >> 5, o = t & 31;
    float v = fmaxf(fmaxf(red[0][j][o], red[1][j][o]),
                    fmaxf(red[2][j][o], red[3][j][o]));
    out[((size_t)b * 32 + o) * 128 + cq * 4 + j] = v;
  }
}

}  // namespace

extern "C" void kernel_launch(void* const* d_in, const int* in_sizes, int n_in,
                              void* d_out, int out_size, void* d_ws, size_t ws_size,
                              hipStream_t stream) {
  const float* images = (const float*)d_in[0];
  const unsigned* rois = (const unsigned*)d_in[1];
  const float* w1 = (const float*)d_in[2];
  const float* b1 = (const float*)d_in[3];
  const float* w2 = (const float*)d_in[4];
  const float* b2 = (const float*)d_in[5];
  const float* dw = (const float*)d_in[6];
  const float* db = (const float*)d_in[7];
  float* out = (float*)d_out;

  char* ws = (char*)d_ws;
  // rmask 256KB @0 ; pooledT 8MB @0x40000 ; Aw2 144KB @0x840000 ; Aw1 20KB @0x864000
  // imgT 8MB @0x900000 (dead after k1) ; x2 32MB @0x900000 (overlaps imgT; written in k2)
  unsigned* rmask = (unsigned*)(ws);
  u16* pooledT = (u16*)(ws + 0x40000);
  u16* Aw2 = (u16*)(ws + 0x840000);
  u16* Aw1 = (u16*)(ws + 0x864000);
  u16* imgT = (u16*)(ws + 0x900000);
  float* x2 = (float*)(ws + 0x900000);

  hipLaunchKernelGGL(k0_rmask, dim3(256), dim3(256), 0, stream, rois, rmask);
  hipLaunchKernelGGL(k0b_imgT, dim3(128, 16), dim3(256), 0, stream, images, imgT);
  hipLaunchKernelGGL(kw_prep, dim3(288), dim3(256), 0, stream, w2, Aw2);
  hipLaunchKernelGGL(kw1_prep, dim3(40), dim3(256), 0, stream, w1, Aw1);
  hipLaunchKernelGGL(k1_mfma, dim3(64, 16), dim3(256), 0, stream, imgT, Aw1, b1, pooledT);
  hipLaunchKernelGGL(k2_mfma, dim3(64, 16), dim3(256), 0, stream, pooledT, Aw2, b2, dw, db, x2);
  hipLaunchKernelGGL(k3_roi, dim3(32, 16), dim3(256), 0, stream, x2, rmask, out);
}

// Round 4
// 114.558 us; speedup vs baseline: 1.1076x; 1.1076x over previous
//
#include <hip/hip_runtime.h>

// B=16, 12 in-ch, 128x128 imgs; conv1->64ch +pool -> 64x64; conv2->128ch (+PE);
// roi max -> out (16,32,128) f32.
//
// Pipeline: k0 (roi bitmask) ; k0b (images -> bf16 [b][row][col][ci16] imgT) ;
// kw/kw1 (weights -> bf16 MFMA-fragment order) ; k1_mfma (conv1+relu+pool ->
// bf16 pooledT [b][ph][pw][co]) ; k2_mfma (conv2+relu+PE -> f32 x2) ; k3 (roi max).

typedef __attribute__((ext_vector_type(8))) short short8;   // MFMA bf16 A/B frag
typedef __attribute__((ext_vector_type(4))) float f32x4;    // MFMA C/D frag
typedef __attribute__((ext_vector_type(4))) unsigned short us4;
typedef unsigned short u16;

__device__ __forceinline__ u16 f2bf(float f) {  // RNE f32 -> bf16 bits
  unsigned u = __builtin_bit_cast(unsigned, f);
  return (u16)((u + 0x7fffu + ((u >> 16) & 1u)) >> 16);
}

namespace {

// ---------------- k0: rois[:,:,::2,::2] -> per-position 32-bit object mask ----
__global__ __launch_bounds__(256) void k0_rmask(const unsigned* __restrict__ rois,
                                                unsigned* __restrict__ rmask) {
  const int lane = threadIdx.x & 63;
  unsigned ok = 1u;
#pragma unroll
  for (int i = 0; i < 4; ++i) {
    unsigned v = rois[lane * 4 + i];
    ok &= ((v <= 1u) || (v == 0x3f800000u)) ? 1u : 0u;
  }
  const bool isWord = (__all((int)ok) != 0);  // 4-byte elements
  const unsigned char* roisB = (const unsigned char*)rois;

  const int pos = blockIdx.x * 256 + threadIdx.x;
  const int b = pos >> 12;
  const int p = pos & 4095;
  const int h = (p >> 6) << 1;
  const int w = (p & 63) << 1;
  const size_t base = (size_t)b * 32 * 16384 + (size_t)h * 128 + (size_t)w;
  unsigned m = 0;
#pragma unroll
  for (int o = 0; o < 32; ++o) {
    const size_t idx = base + (size_t)o * 16384;
    unsigned bit = isWord ? (unsigned)(rois[idx] != 0u) : (unsigned)(roisB[idx] != 0);
    m |= bit << o;
  }
  rmask[pos] = m;
}

// ---------------- k0b: images f32 [b][12][128][128] -> bf16 imgT [b][row][col][16] (ci pad->0)
__global__ __launch_bounds__(256) void k0b_imgT(const float* __restrict__ img,
                                                u16* __restrict__ imgT) {
  __shared__ alignas(16) u16 ST[2048];  // [col 0..127][cip 0..15]
  const int row = blockIdx.x, b = blockIdx.y;
  const int t = threadIdx.x;
#pragma unroll
  for (int i = 0; i < 2; ++i) {  // zero pads cip 12..15
    const int e = i * 256 + t;   // 0..511
    ST[(e >> 2) * 16 + 12 + (e & 3)] = 0;
  }
#pragma unroll
  for (int i = 0; i < 6; ++i) {  // 12 ci x 128 col
    const int e = i * 256 + t;   // 0..1535
    const int ci = e >> 7, col = e & 127;
    const float v = img[(((size_t)(b * 12 + ci)) << 14) + row * 128 + col];
    ST[col * 16 + ci] = f2bf(v);
  }
  __syncthreads();
  us4* dst = (us4*)(imgT + (((size_t)(b * 128 + row)) << 11));
#pragma unroll
  for (int i = 0; i < 2; ++i) {
    const int q = i * 256 + t;  // 0..511 us4 chunks
    dst[q] = *(const us4*)&ST[q * 4];
  }
}

// ---------------- kw: w2 f32 [co][64][3][3] -> bf16 A-fragments, K-order k=32ks+g*8+j,
// k -> (rc = k>>6, ci = k&63), src = w2[co*576 + ci*9 + rc]. idx=((cot*18+ks)*64+lane)*8+j
__global__ __launch_bounds__(256) void kw_prep(const float* __restrict__ w2,
                                               u16* __restrict__ Aw) {
  const int idx = blockIdx.x * 256 + threadIdx.x;  // 0..73727
  const int j = idx & 7;
  const int lane = (idx >> 3) & 63;
  const int t3 = idx >> 9;
  const int ks = t3 % 18, cot = t3 / 18;
  const int m = lane & 15, g = lane >> 4;
  const int co = cot * 16 + m;
  const int k = ks * 32 + g * 8 + j;
  const int rc = k >> 6, ci = k & 63;
  Aw[idx] = f2bf(w2[co * 576 + ci * 9 + rc]);
}

// ---------------- kw1: w1 f32 [co][12][3][3] -> bf16 A-frags, K padded 108->160.
// k=32ks+g*8+j -> (rc=k>>4, cip=k&15); pad (rc>=9 || cip>=12) -> 0.
__global__ __launch_bounds__(256) void kw1_prep(const float* __restrict__ w1,
                                                u16* __restrict__ Aw1) {
  const int idx = blockIdx.x * 256 + threadIdx.x;  // 0..10239
  const int j = idx & 7;
  const int lane = (idx >> 3) & 63;
  const int t3 = idx >> 9;           // cot*5 + ks
  const int ks = t3 % 5, cot = t3 / 5;
  const int m = lane & 15, g = lane >> 4;
  const int co = cot * 16 + m;
  const int k = ks * 32 + g * 8 + j;
  const int rc = k >> 4, cip = k & 15;
  const float v = (rc < 9 && cip < 12) ? w1[co * 108 + cip * 9 + rc] : 0.f;
  Aw1[idx] = f2bf(v);
}

// ---------------- k1: conv1 (MFMA) + bias + relu + pool -> pooledT bf16 [b][ph][pw][co]
// block: (h2 = pooled row, b). Stages img rows 2h2-1..2h2+2 as [4][128 col][16 cip].
// wave wv: co-tiles {2(wv&1), +1} x cols [ (wv>>1)*64, +64 ) x conv rows {2h2, 2h2+1}.
__global__ __launch_bounds__(256) void k1_mfma(const u16* __restrict__ imgT,
                                               const u16* __restrict__ Aw1,
                                               const float* __restrict__ b1,
                                               u16* __restrict__ pooledT) {
  __shared__ alignas(16) u16 SIMG[8192];     // 16 KB
  __shared__ alignas(16) u16 PT[64 * 68];    // pooled [pw][co], pad-68 stride
  const int h2 = blockIdx.x, b = blockIdx.y;
  const int t = threadIdx.x, wv = t >> 6, l = t & 63;

#pragma unroll
  for (int i = 0; i < 4; ++i) {  // stage 4 rows x 4KB
    const int q = i * 256 + t;   // 16B chunk 0..1023
    const int sr = q >> 8, off = q & 255;
    const int irow = 2 * h2 - 1 + sr;
    short8 v = {0, 0, 0, 0, 0, 0, 0, 0};
    if ((unsigned)irow < 128u)
      v = *(const short8*)(imgT + (((size_t)(b * 128 + irow)) << 11) + off * 8);
    *(short8*)(SIMG + q * 8) = v;
  }
  __syncthreads();

  const int m16 = l & 15, g = l >> 4;
  const int colhalf = wv >> 1, cotbase = (wv & 1) * 2;
  f32x4 acc[2][8];
#pragma unroll
  for (int ct = 0; ct < 2; ++ct)
#pragma unroll
    for (int pt = 0; pt < 8; ++pt) acc[ct][pt] = (f32x4){0.f, 0.f, 0.f, 0.f};

  const u16* awb = Aw1 + (size_t)l * 8;
  const int cipb = (g & 1) * 16;  // byte offset of cip0 within 32B col-slot

#pragma unroll
  for (int ks = 0; ks < 5; ++ks) {
    short8 a0 = *(const short8*)(awb + (cotbase * 5 + ks) * 512);
    short8 a1 = *(const short8*)(awb + ((cotbase + 1) * 5 + ks) * 512);
    const bool pad = (ks == 4) && (g >= 2);  // k in [144,160): zero slots
    int rc = pad ? 0 : (2 * ks + (g >> 1));  // 0..8
    const int rr = (rc * 11) >> 5;           // rc/3
    const int cc = rc - rr * 3;              // rc%3
#pragma unroll
    for (int pt = 0; pt < 8; ++pt) {
      const int r01 = pt >> 2, ct2 = pt & 3;
      const int icol = colhalf * 64 + ct2 * 16 + m16 - 1 + cc;  // -1..128
      const bool ok = ((unsigned)icol < 128u) && !pad;
      const int ic = ok ? icol : 0;
      const int sr = r01 + rr;  // 0..3 (pad forces rr=0)
      short8 bv = *(const short8*)((const char*)SIMG + sr * 4096 + ic * 32 + cipb);
      if (!ok) bv = (short8){0, 0, 0, 0, 0, 0, 0, 0};
      acc[0][pt] = __builtin_amdgcn_mfma_f32_16x16x32_bf16(a0, bv, acc[0][pt], 0, 0, 0);
      acc[1][pt] = __builtin_amdgcn_mfma_f32_16x16x32_bf16(a1, bv, acc[1][pt], 0, 0, 0);
    }
  }

  // relu + 2x2 pool (rows in-lane, col pairs via shfl_xor) -> PT[pw][co]
#pragma unroll
  for (int ct = 0; ct < 2; ++ct) {
    const int cot = cotbase + ct;
#pragma unroll
    for (int r = 0; r < 4; ++r) {
      const int co = cot * 16 + g * 4 + r;
      const float bias = b1[co];
#pragma unroll
      for (int ct2 = 0; ct2 < 4; ++ct2) {
        float v0 = fmaxf(acc[ct][ct2][r] + bias, 0.f);
        float v1 = fmaxf(acc[ct][4 + ct2][r] + bias, 0.f);
        float vv = fmaxf(v0, v1);
        vv = fmaxf(vv, __shfl_xor(vv, 1, 64));
        if (!(m16 & 1)) {
          const int pw = colhalf * 32 + ct2 * 8 + (m16 >> 1);
          PT[pw * 68 + co] = f2bf(vv);
        }
      }
    }
  }
  __syncthreads();
  u16* dst = pooledT + (((size_t)(b * 64 + h2)) << 12);
#pragma unroll
  for (int i = 0; i < 4; ++i) {
    const int e = (i * 256 + t) * 4;
    const int pw = e >> 6, co = e & 63;
    *(us4*)(dst + e) = *(const us4*)&PT[pw * 68 + co];
  }
}

// ---------------- k2: conv2 (MFMA) + bias + relu + PE -> x2 f32 [b][co][h][w]
// block: (h, b). Stages pooledT rows h-1..h+1 as [3][64 col][64 ci], XOR-swizzled.
// wave wv: co-tiles {2wv, 2wv+1} x all 64 cols (4 pos-tiles). K = 576 = 18 ksteps.
__global__ __launch_bounds__(256) void k2_mfma(const u16* __restrict__ pooledT,
                                               const u16* __restrict__ Aw,
                                               const float* __restrict__ b2,
                                               const float* __restrict__ dw,
                                               const float* __restrict__ db,
                                               float* __restrict__ x2) {
  __shared__ alignas(16) short8 SIN8[1536];  // 24 KB
  char* SB = (char*)SIN8;
  const int h = blockIdx.x, b = blockIdx.y;
  const int t = threadIdx.x, wv = t >> 6, l = t & 63;

#pragma unroll
  for (int i = 0; i < 6; ++i) {  // 24 chunks x 1KB
    const int chunk = i * 4 + wv;
    const int row = chunk >> 3;
    const int hin = h - 1 + row;
    short8 v = {0, 0, 0, 0, 0, 0, 0, 0};
    if ((unsigned)hin < 64u)
      v = *(const short8*)(pooledT + (((size_t)(b * 64 + hin)) << 12) +
                           ((chunk & 7) << 9) + l * 8);
    const int lin = chunk * 1024 + l * 16;
    *(short8*)(SB + (lin ^ (((lin >> 7) & 7) << 4))) = v;  // T2 XOR swizzle
  }
  __syncthreads();

  const int m16 = l & 15, g = l >> 4;
  const int kbyte = g * 16;
  f32x4 acc[2][4];
#pragma unroll
  for (int ct = 0; ct < 2; ++ct)
#pragma unroll
    for (int n = 0; n < 4; ++n) acc[ct][n] = (f32x4){0.f, 0.f, 0.f, 0.f};

  const u16* aw0 = Aw + (size_t)wv * 36 * 512 + l * 8;  // cot = 2wv

#pragma unroll
  for (int ks = 0; ks < 18; ++ks) {
    const int rc = ks >> 1, r = rc / 3, c = rc % 3;  // compile-time
    const int koff = r * 8192 + (ks & 1) * 64 + kbyte;
    short8 a0 = *(const short8*)(aw0 + ks * 512);
    short8 a1 = *(const short8*)(aw0 + (18 + ks) * 512);
    const int d = m16 + c - 1;  // -1..16
#pragma unroll
    for (int n = 0; n < 4; ++n) {
      const int icol = n * 16 + d;
      const bool ok = (unsigned)icol < 64u;
      const int ic = ok ? icol : (icol < 0 ? 0 : 63);
      int addr = koff + ic * 128;
      addr ^= (ic & 7) << 4;  // matching read-side swizzle
      short8 bv = *(const short8*)(SB + addr);
      if (!ok) bv = (short8){0, 0, 0, 0, 0, 0, 0, 0};
      acc[0][n] = __builtin_amdgcn_mfma_f32_16x16x32_bf16(a0, bv, acc[0][n], 0, 0, 0);
      acc[1][n] = __builtin_amdgcn_mfma_f32_16x16x32_bf16(a1, bv, acc[1][n], 0, 0, 0);
    }
  }

  // epilogue: relu(acc + b2) + pe ; pe = gy*(W0-W2) + gx*(W1-W3) + W2+W3+db
  const float inv63 = 1.f / 63.f;
  const float gy = (float)h * inv63;
#pragma unroll
  for (int ct = 0; ct < 2; ++ct) {
    const int cot = wv * 2 + ct;
#pragma unroll
    for (int r = 0; r < 4; ++r) {
      const int co = cot * 16 + g * 4 + r;
      const float bias = b2[co];
      const float W0 = dw[co * 4 + 0], W1 = dw[co * 4 + 1];
      const float W2 = dw[co * 4 + 2], W3 = dw[co * 4 + 3];
      const float pe0 = gy * (W0 - W2) + W2 + W3 + db[co];
      const float s13 = W1 - W3;
      float* orow = x2 + (((size_t)(b * 128 + co)) << 12) + h * 64;
#pragma unroll
      for (int n = 0; n < 4; ++n) {
        const int w = n * 16 + m16;
        orow[w] = fmaxf(acc[ct][n][r] + bias, 0.f) + pe0 + (float)w * inv63 * s13;
      }
    }
  }
}

// ---------------- k3: out[b,o,c] = max over pos of x2[b,c,pos] * r[b,o,pos] ---
// v3: block = (c-quad, b). Thread scans 16 pos for 4 c-planes; mask decode
// (2 ops) shared across the 4 planes (and+max each). ALL indices into the
// m[4][32] accumulator array are compile-time constants (rule #20: a single
// runtime index demotes the whole array to scratch -- R3's 153MB WRITE_SIZE).
__global__ __launch_bounds__(256, 2) void k3_roi(const float* __restrict__ x2,
                                                 const unsigned* __restrict__ rmask,
                                                 float* __restrict__ out) {
  __shared__ float red[4][4][32];  // [wave][cj][o]
  const int cq = blockIdx.x, b = blockIdx.y;
  const int t = threadIdx.x, wv = t >> 6;
  const float* p0 = x2 + ((size_t)(b * 128 + cq * 4)) * 4096;
  const unsigned* mb = rmask + b * 4096;

  float m[4][32];
#pragma unroll
  for (int j = 0; j < 4; ++j)
#pragma unroll
    for (int o = 0; o < 32; ++o) m[j][o] = -3.4e38f;

  for (int k = 0; k < 16; ++k) {
    const int pos = k * 256 + t;
    const unsigned mk = mb[pos];
    float xv[4];
#pragma unroll
    for (int j = 0; j < 4; ++j) xv[j] = p0[j * 4096 + pos];
#pragma unroll
    for (int o = 0; o < 32; ++o) {
      const unsigned am = (unsigned)((int)(mk << (31 - o)) >> 31);  // bit o -> 0/~0
#pragma unroll
      for (int j = 0; j < 4; ++j) {
        const float sel = __builtin_bit_cast(
            float, __builtin_bit_cast(unsigned, xv[j]) & am);
        m[j][o] = fmaxf(m[j][o], sel);
      }
    }
  }

  // in-wave butterfly per accumulator, then 4-way cross-wave merge via LDS
#pragma unroll
  for (int j = 0; j < 4; ++j)
#pragma unroll
    for (int o = 0; o < 32; ++o) {
#pragma unroll
      for (int s = 32; s >= 1; s >>= 1)
        m[j][o] = fmaxf(m[j][o], __shfl_xor(m[j][o], s, 64));
    }
  const int lane = t & 63;
  if (lane == 0) {  // static indices only -- keeps m[][] in VGPRs
#pragma unroll
    for (int j = 0; j < 4; ++j)
#pragma unroll
      for (int o = 0; o < 32; ++o) red[wv][j][o] = m[j][o];
  }
  __syncthreads();
  if (t < 128) {
    const int j = t >> 5, o = t & 31;
    float v = fmaxf(fmaxf(red[0][j][o], red[1][j][o]),
                    fmaxf(red[2][j][o], red[3][j][o]));
    out[((size_t)b * 32 + o) * 128 + cq * 4 + j] = v;
  }
}

}  // namespace

extern "C" void kernel_launch(void* const* d_in, const int* in_sizes, int n_in,
                              void* d_out, int out_size, void* d_ws, size_t ws_size,
                              hipStream_t stream) {
  const float* images = (const float*)d_in[0];
  const unsigned* rois = (const unsigned*)d_in[1];
  const float* w1 = (const float*)d_in[2];
  const float* b1 = (const float*)d_in[3];
  const float* w2 = (const float*)d_in[4];
  const float* b2 = (const float*)d_in[5];
  const float* dw = (const float*)d_in[6];
  const float* db = (const float*)d_in[7];
  float* out = (float*)d_out;

  char* ws = (char*)d_ws;
  // rmask 256KB @0 ; pooledT 8MB @0x40000 ; Aw2 144KB @0x840000 ; Aw1 20KB @0x864000
  // imgT 8MB @0x900000 (dead after k1) ; x2 32MB @0x900000 (overlaps imgT; written in k2)
  unsigned* rmask = (unsigned*)(ws);
  u16* pooledT = (u16*)(ws + 0x40000);
  u16* Aw2 = (u16*)(ws + 0x840000);
  u16* Aw1 = (u16*)(ws + 0x864000);
  u16* imgT = (u16*)(ws + 0x900000);
  float* x2 = (float*)(ws + 0x900000);

  hipLaunchKernelGGL(k0_rmask, dim3(256), dim3(256), 0, stream, rois, rmask);
  hipLaunchKernelGGL(k0b_imgT, dim3(128, 16), dim3(256), 0, stream, images, imgT);
  hipLaunchKernelGGL(kw_prep, dim3(288), dim3(256), 0, stream, w2, Aw2);
  hipLaunchKernelGGL(kw1_prep, dim3(40), dim3(256), 0, stream, w1, Aw1);
  hipLaunchKernelGGL(k1_mfma, dim3(64, 16), dim3(256), 0, stream, imgT, Aw1, b1, pooledT);
  hipLaunchKernelGGL(k2_mfma, dim3(64, 16), dim3(256), 0, stream, pooledT, Aw2, b2, dw, db, x2);
  hipLaunchKernelGGL(k3_roi, dim3(32, 16), dim3(256), 0, stream, x2, rmask, out);
}

// Round 5
// 93.440 us; speedup vs baseline: 1.3579x; 1.2260x over previous
//
#include <hip/hip_runtime.h>

// B=16, 12 in-ch, 128x128 imgs; conv1->64ch +pool -> 64x64; conv2->128ch (+PE);
// roi max -> out (16,32,128) f32.
//
// Pipeline: k0 (roi bitmask) ; k0b (images -> bf16 [b][row][col][ci16] imgT) ;
// kw/kw1 (weights -> bf16 MFMA-fragment order) ; k1_mfma (conv1+relu+pool ->
// bf16 pooledT [b][ph][pw][co]) ; k2_mfma (conv2+relu+PE -> f32 x2) ; k3 (roi max).

typedef __attribute__((ext_vector_type(8))) short short8;   // MFMA bf16 A/B frag
typedef __attribute__((ext_vector_type(4))) float f32x4;    // MFMA C/D frag
typedef __attribute__((ext_vector_type(4))) unsigned short us4;
typedef unsigned short u16;

__device__ __forceinline__ u16 f2bf(float f) {  // RNE f32 -> bf16 bits
  unsigned u = __builtin_bit_cast(unsigned, f);
  return (u16)((u + 0x7fffu + ((u >> 16) & 1u)) >> 16);
}

namespace {

// ---------------- k0: rois[:,:,::2,::2] -> per-position 32-bit object mask ----
__global__ __launch_bounds__(256) void k0_rmask(const unsigned* __restrict__ rois,
                                                unsigned* __restrict__ rmask) {
  const int lane = threadIdx.x & 63;
  unsigned ok = 1u;
#pragma unroll
  for (int i = 0; i < 4; ++i) {
    unsigned v = rois[lane * 4 + i];
    ok &= ((v <= 1u) || (v == 0x3f800000u)) ? 1u : 0u;
  }
  const bool isWord = (__all((int)ok) != 0);  // 4-byte elements
  const unsigned char* roisB = (const unsigned char*)rois;

  const int pos = blockIdx.x * 256 + threadIdx.x;
  const int b = pos >> 12;
  const int p = pos & 4095;
  const int h = (p >> 6) << 1;
  const int w = (p & 63) << 1;
  const size_t base = (size_t)b * 32 * 16384 + (size_t)h * 128 + (size_t)w;
  unsigned m = 0;
#pragma unroll
  for (int o = 0; o < 32; ++o) {
    const size_t idx = base + (size_t)o * 16384;
    unsigned bit = isWord ? (unsigned)(rois[idx] != 0u) : (unsigned)(roisB[idx] != 0);
    m |= bit << o;
  }
  rmask[pos] = m;
}

// ---------------- k0b: images f32 [b][12][128][128] -> bf16 imgT [b][row][col][16] (ci pad->0)
__global__ __launch_bounds__(256) void k0b_imgT(const float* __restrict__ img,
                                                u16* __restrict__ imgT) {
  __shared__ alignas(16) u16 ST[2048];  // [col 0..127][cip 0..15]
  const int row = blockIdx.x, b = blockIdx.y;
  const int t = threadIdx.x;
#pragma unroll
  for (int i = 0; i < 2; ++i) {  // zero pads cip 12..15
    const int e = i * 256 + t;   // 0..511
    ST[(e >> 2) * 16 + 12 + (e & 3)] = 0;
  }
#pragma unroll
  for (int i = 0; i < 6; ++i) {  // 12 ci x 128 col
    const int e = i * 256 + t;   // 0..1535
    const int ci = e >> 7, col = e & 127;
    const float v = img[(((size_t)(b * 12 + ci)) << 14) + row * 128 + col];
    ST[col * 16 + ci] = f2bf(v);
  }
  __syncthreads();
  us4* dst = (us4*)(imgT + (((size_t)(b * 128 + row)) << 11));
#pragma unroll
  for (int i = 0; i < 2; ++i) {
    const int q = i * 256 + t;  // 0..511 us4 chunks
    dst[q] = *(const us4*)&ST[q * 4];
  }
}

// ---------------- kw: w2 f32 [co][64][3][3] -> bf16 A-fragments, K-order k=32ks+g*8+j,
// k -> (rc = k>>6, ci = k&63), src = w2[co*576 + ci*9 + rc]. idx=((cot*18+ks)*64+lane)*8+j
__global__ __launch_bounds__(256) void kw_prep(const float* __restrict__ w2,
                                               u16* __restrict__ Aw) {
  const int idx = blockIdx.x * 256 + threadIdx.x;  // 0..73727
  const int j = idx & 7;
  const int lane = (idx >> 3) & 63;
  const int t3 = idx >> 9;
  const int ks = t3 % 18, cot = t3 / 18;
  const int m = lane & 15, g = lane >> 4;
  const int co = cot * 16 + m;
  const int k = ks * 32 + g * 8 + j;
  const int rc = k >> 6, ci = k & 63;
  Aw[idx] = f2bf(w2[co * 576 + ci * 9 + rc]);
}

// ---------------- kw1: w1 f32 [co][12][3][3] -> bf16 A-frags, K padded 108->160.
// k=32ks+g*8+j -> (rc=k>>4, cip=k&15); pad (rc>=9 || cip>=12) -> 0.
__global__ __launch_bounds__(256) void kw1_prep(const float* __restrict__ w1,
                                                u16* __restrict__ Aw1) {
  const int idx = blockIdx.x * 256 + threadIdx.x;  // 0..10239
  const int j = idx & 7;
  const int lane = (idx >> 3) & 63;
  const int t3 = idx >> 9;           // cot*5 + ks
  const int ks = t3 % 5, cot = t3 / 5;
  const int m = lane & 15, g = lane >> 4;
  const int co = cot * 16 + m;
  const int k = ks * 32 + g * 8 + j;
  const int rc = k >> 4, cip = k & 15;
  const float v = (rc < 9 && cip < 12) ? w1[co * 108 + cip * 9 + rc] : 0.f;
  Aw1[idx] = f2bf(v);
}

// ---------------- k1: conv1 (MFMA) + bias + relu + pool -> pooledT bf16 [b][ph][pw][co]
// block: (h2 = pooled row, b). Stages img rows 2h2-1..2h2+2 as [4][128 col][16 cip].
// wave wv: co-tiles {2(wv&1), +1} x cols [ (wv>>1)*64, +64 ) x conv rows {2h2, 2h2+1}.
__global__ __launch_bounds__(256) void k1_mfma(const u16* __restrict__ imgT,
                                               const u16* __restrict__ Aw1,
                                               const float* __restrict__ b1,
                                               u16* __restrict__ pooledT) {
  __shared__ alignas(16) u16 SIMG[8192];     // 16 KB
  __shared__ alignas(16) u16 PT[64 * 68];    // pooled [pw][co], pad-68 stride
  const int h2 = blockIdx.x, b = blockIdx.y;
  const int t = threadIdx.x, wv = t >> 6, l = t & 63;

#pragma unroll
  for (int i = 0; i < 4; ++i) {  // stage 4 rows x 4KB
    const int q = i * 256 + t;   // 16B chunk 0..1023
    const int sr = q >> 8, off = q & 255;
    const int irow = 2 * h2 - 1 + sr;
    short8 v = {0, 0, 0, 0, 0, 0, 0, 0};
    if ((unsigned)irow < 128u)
      v = *(const short8*)(imgT + (((size_t)(b * 128 + irow)) << 11) + off * 8);
    *(short8*)(SIMG + q * 8) = v;
  }
  __syncthreads();

  const int m16 = l & 15, g = l >> 4;
  const int colhalf = wv >> 1, cotbase = (wv & 1) * 2;
  f32x4 acc[2][8];
#pragma unroll
  for (int ct = 0; ct < 2; ++ct)
#pragma unroll
    for (int pt = 0; pt < 8; ++pt) acc[ct][pt] = (f32x4){0.f, 0.f, 0.f, 0.f};

  const u16* awb = Aw1 + (size_t)l * 8;
  const int cipb = (g & 1) * 16;  // byte offset of cip0 within 32B col-slot

#pragma unroll
  for (int ks = 0; ks < 5; ++ks) {
    short8 a0 = *(const short8*)(awb + (cotbase * 5 + ks) * 512);
    short8 a1 = *(const short8*)(awb + ((cotbase + 1) * 5 + ks) * 512);
    const bool pad = (ks == 4) && (g >= 2);  // k in [144,160): zero slots
    int rc = pad ? 0 : (2 * ks + (g >> 1));  // 0..8
    const int rr = (rc * 11) >> 5;           // rc/3
    const int cc = rc - rr * 3;              // rc%3
#pragma unroll
    for (int pt = 0; pt < 8; ++pt) {
      const int r01 = pt >> 2, ct2 = pt & 3;
      const int icol = colhalf * 64 + ct2 * 16 + m16 - 1 + cc;  // -1..128
      const bool ok = ((unsigned)icol < 128u) && !pad;
      const int ic = ok ? icol : 0;
      const int sr = r01 + rr;  // 0..3 (pad forces rr=0)
      short8 bv = *(const short8*)((const char*)SIMG + sr * 4096 + ic * 32 + cipb);
      if (!ok) bv = (short8){0, 0, 0, 0, 0, 0, 0, 0};
      acc[0][pt] = __builtin_amdgcn_mfma_f32_16x16x32_bf16(a0, bv, acc[0][pt], 0, 0, 0);
      acc[1][pt] = __builtin_amdgcn_mfma_f32_16x16x32_bf16(a1, bv, acc[1][pt], 0, 0, 0);
    }
  }

  // relu + 2x2 pool (rows in-lane, col pairs via shfl_xor) -> PT[pw][co]
#pragma unroll
  for (int ct = 0; ct < 2; ++ct) {
    const int cot = cotbase + ct;
#pragma unroll
    for (int r = 0; r < 4; ++r) {
      const int co = cot * 16 + g * 4 + r;
      const float bias = b1[co];
#pragma unroll
      for (int ct2 = 0; ct2 < 4; ++ct2) {
        float v0 = fmaxf(acc[ct][ct2][r] + bias, 0.f);
        float v1 = fmaxf(acc[ct][4 + ct2][r] + bias, 0.f);
        float vv = fmaxf(v0, v1);
        vv = fmaxf(vv, __shfl_xor(vv, 1, 64));
        if (!(m16 & 1)) {
          const int pw = colhalf * 32 + ct2 * 8 + (m16 >> 1);
          PT[pw * 68 + co] = f2bf(vv);
        }
      }
    }
  }
  __syncthreads();
  u16* dst = pooledT + (((size_t)(b * 64 + h2)) << 12);
#pragma unroll
  for (int i = 0; i < 4; ++i) {
    const int e = (i * 256 + t) * 4;
    const int pw = e >> 6, co = e & 63;
    *(us4*)(dst + e) = *(const us4*)&PT[pw * 68 + co];
  }
}

// ---------------- k2: conv2 (MFMA) + bias + relu + PE -> x2 f32 [b][co][h][w]
// block: (h, b). Stages pooledT rows h-1..h+1 as [3][64 col][64 ci], XOR-swizzled.
// wave wv: co-tiles {2wv, 2wv+1} x all 64 cols (4 pos-tiles). K = 576 = 18 ksteps.
__global__ __launch_bounds__(256) void k2_mfma(const u16* __restrict__ pooledT,
                                               const u16* __restrict__ Aw,
                                               const float* __restrict__ b2,
                                               const float* __restrict__ dw,
                                               const float* __restrict__ db,
                                               float* __restrict__ x2) {
  __shared__ alignas(16) short8 SIN8[1536];  // 24 KB
  char* SB = (char*)SIN8;
  const int h = blockIdx.x, b = blockIdx.y;
  const int t = threadIdx.x, wv = t >> 6, l = t & 63;

#pragma unroll
  for (int i = 0; i < 6; ++i) {  // 24 chunks x 1KB
    const int chunk = i * 4 + wv;
    const int row = chunk >> 3;
    const int hin = h - 1 + row;
    short8 v = {0, 0, 0, 0, 0, 0, 0, 0};
    if ((unsigned)hin < 64u)
      v = *(const short8*)(pooledT + (((size_t)(b * 64 + hin)) << 12) +
                           ((chunk & 7) << 9) + l * 8);
    const int lin = chunk * 1024 + l * 16;
    *(short8*)(SB + (lin ^ (((lin >> 7) & 7) << 4))) = v;  // T2 XOR swizzle
  }
  __syncthreads();

  const int m16 = l & 15, g = l >> 4;
  const int kbyte = g * 16;
  f32x4 acc[2][4];
#pragma unroll
  for (int ct = 0; ct < 2; ++ct)
#pragma unroll
    for (int n = 0; n < 4; ++n) acc[ct][n] = (f32x4){0.f, 0.f, 0.f, 0.f};

  const u16* aw0 = Aw + (size_t)wv * 36 * 512 + l * 8;  // cot = 2wv

#pragma unroll
  for (int ks = 0; ks < 18; ++ks) {
    const int rc = ks >> 1, r = rc / 3, c = rc % 3;  // compile-time
    const int koff = r * 8192 + (ks & 1) * 64 + kbyte;
    short8 a0 = *(const short8*)(aw0 + ks * 512);
    short8 a1 = *(const short8*)(aw0 + (18 + ks) * 512);
    const int d = m16 + c - 1;  // -1..16
#pragma unroll
    for (int n = 0; n < 4; ++n) {
      const int icol = n * 16 + d;
      const bool ok = (unsigned)icol < 64u;
      const int ic = ok ? icol : (icol < 0 ? 0 : 63);
      int addr = koff + ic * 128;
      addr ^= (ic & 7) << 4;  // matching read-side swizzle
      short8 bv = *(const short8*)(SB + addr);
      if (!ok) bv = (short8){0, 0, 0, 0, 0, 0, 0, 0};
      acc[0][n] = __builtin_amdgcn_mfma_f32_16x16x32_bf16(a0, bv, acc[0][n], 0, 0, 0);
      acc[1][n] = __builtin_amdgcn_mfma_f32_16x16x32_bf16(a1, bv, acc[1][n], 0, 0, 0);
    }
  }

  // epilogue: relu(acc + b2) + pe ; pe = gy*(W0-W2) + gx*(W1-W3) + W2+W3+db
  const float inv63 = 1.f / 63.f;
  const float gy = (float)h * inv63;
#pragma unroll
  for (int ct = 0; ct < 2; ++ct) {
    const int cot = wv * 2 + ct;
#pragma unroll
    for (int r = 0; r < 4; ++r) {
      const int co = cot * 16 + g * 4 + r;
      const float bias = b2[co];
      const float W0 = dw[co * 4 + 0], W1 = dw[co * 4 + 1];
      const float W2 = dw[co * 4 + 2], W3 = dw[co * 4 + 3];
      const float pe0 = gy * (W0 - W2) + W2 + W3 + db[co];
      const float s13 = W1 - W3;
      float* orow = x2 + (((size_t)(b * 128 + co)) << 12) + h * 64;
#pragma unroll
      for (int n = 0; n < 4; ++n) {
        const int w = n * 16 + m16;
        orow[w] = fmaxf(acc[ct][n][r] + bias, 0.f) + pe0 + (float)w * inv63 * s13;
      }
    }
  }
}

// ---------------- k3: out[b,o,c] = max over pos of x2[b,c,pos] * r[b,o,pos] ---
// v4: block = (c-pair, b) -> 1024 blocks (4 waves/SIMD). Thread: 2 planes,
// 2 positions/iter (float2/uint2 loads). Per o: 2x bfe decode shared across
// 2 pos; per plane the two selects fold into v_max3 via nested fmaxf (T17).
// m[2][32] = 64 accums + ~25 temps -> register-resident at launch_bounds(256,4)
// (R4 lesson: 128 accums filled the whole VGPR budget -> AGPR ping-pong).
// All m[][] indices compile-time (rule #20).
__global__ __launch_bounds__(256, 4) void k3_roi(const float* __restrict__ x2,
                                                 const unsigned* __restrict__ rmask,
                                                 float* __restrict__ out) {
  __shared__ float red[4][2][32];  // [wave][cj][o]
  const int cp = blockIdx.x, b = blockIdx.y;
  const int t = threadIdx.x, wv = t >> 6;
  const float* p0 = x2 + ((size_t)(b * 128 + cp * 2)) * 4096;
  const float* p1 = p0 + 4096;
  const unsigned* mb = rmask + b * 4096;

  float m[2][32];
#pragma unroll
  for (int j = 0; j < 2; ++j)
#pragma unroll
    for (int o = 0; o < 32; ++o) m[j][o] = -3.4e38f;

  for (int k = 0; k < 8; ++k) {
    const int pos = k * 512 + t * 2;
    const uint2 mk = *(const uint2*)&mb[pos];
    const float2 va = *(const float2*)&p0[pos];
    const float2 vb = *(const float2*)&p1[pos];
    const unsigned ax = __builtin_bit_cast(unsigned, va.x);
    const unsigned ay = __builtin_bit_cast(unsigned, va.y);
    const unsigned bx = __builtin_bit_cast(unsigned, vb.x);
    const unsigned by = __builtin_bit_cast(unsigned, vb.y);
#pragma unroll
    for (int o = 0; o < 32; ++o) {
      const unsigned am0 = (unsigned)((int)(mk.x << (31 - o)) >> 31);  // v_bfe_i32
      const unsigned am1 = (unsigned)((int)(mk.y << (31 - o)) >> 31);
      const float s0a = __builtin_bit_cast(float, ax & am0);
      const float s1a = __builtin_bit_cast(float, ay & am1);
      const float s0b = __builtin_bit_cast(float, bx & am0);
      const float s1b = __builtin_bit_cast(float, by & am1);
      m[0][o] = fmaxf(fmaxf(m[0][o], s0a), s1a);  // -> v_max3_f32
      m[1][o] = fmaxf(fmaxf(m[1][o], s0b), s1b);
    }
  }

  // in-wave butterfly per accumulator, then 4-way cross-wave merge via LDS
#pragma unroll
  for (int j = 0; j < 2; ++j)
#pragma unroll
    for (int o = 0; o < 32; ++o) {
#pragma unroll
      for (int s = 32; s >= 1; s >>= 1)
        m[j][o] = fmaxf(m[j][o], __shfl_xor(m[j][o], s, 64));
    }
  const int lane = t & 63;
  if (lane == 0) {  // static indices only -- keeps m[][] in VGPRs
#pragma unroll
    for (int j = 0; j < 2; ++j)
#pragma unroll
      for (int o = 0; o < 32; ++o) red[wv][j][o] = m[j][o];
  }
  __syncthreads();
  if (t < 64) {
    const int j = t >> 5, o = t & 31;
    float v = fmaxf(fmaxf(red[0][j][o], red[1][j][o]),
                    fmaxf(red[2][j][o], red[3][j][o]));
    out[((size_t)b * 32 + o) * 128 + cp * 2 + j] = v;
  }
}

}  // namespace

extern "C" void kernel_launch(void* const* d_in, const int* in_sizes, int n_in,
                              void* d_out, int out_size, void* d_ws, size_t ws_size,
                              hipStream_t stream) {
  const float* images = (const float*)d_in[0];
  const unsigned* rois = (const unsigned*)d_in[1];
  const float* w1 = (const float*)d_in[2];
  const float* b1 = (const float*)d_in[3];
  const float* w2 = (const float*)d_in[4];
  const float* b2 = (const float*)d_in[5];
  const float* dw = (const float*)d_in[6];
  const float* db = (const float*)d_in[7];
  float* out = (float*)d_out;

  char* ws = (char*)d_ws;
  // rmask 256KB @0 ; pooledT 8MB @0x40000 ; Aw2 144KB @0x840000 ; Aw1 20KB @0x864000
  // imgT 8MB @0x900000 (dead after k1) ; x2 32MB @0x900000 (overlaps imgT; written in k2)
  unsigned* rmask = (unsigned*)(ws);
  u16* pooledT = (u16*)(ws + 0x40000);
  u16* Aw2 = (u16*)(ws + 0x840000);
  u16* Aw1 = (u16*)(ws + 0x864000);
  u16* imgT = (u16*)(ws + 0x900000);
  float* x2 = (float*)(ws + 0x900000);

  hipLaunchKernelGGL(k0_rmask, dim3(256), dim3(256), 0, stream, rois, rmask);
  hipLaunchKernelGGL(k0b_imgT, dim3(128, 16), dim3(256), 0, stream, images, imgT);
  hipLaunchKernelGGL(kw_prep, dim3(288), dim3(256), 0, stream, w2, Aw2);
  hipLaunchKernelGGL(kw1_prep, dim3(40), dim3(256), 0, stream, w1, Aw1);
  hipLaunchKernelGGL(k1_mfma, dim3(64, 16), dim3(256), 0, stream, imgT, Aw1, b1, pooledT);
  hipLaunchKernelGGL(k2_mfma, dim3(64, 16), dim3(256), 0, stream, pooledT, Aw2, b2, dw, db, x2);
  hipLaunchKernelGGL(k3_roi, dim3(64, 16), dim3(256), 0, stream, x2, rmask, out);
}

// Round 6
// 83.294 us; speedup vs baseline: 1.5233x; 1.1218x over previous
//
#include <hip/hip_runtime.h>

// B=16, 12 in-ch, 128x128 imgs; conv1->64ch +pool -> 64x64; conv2->128ch (+PE);
// roi max -> out (16,32,128) f32.
//
// Pipeline: k0 (roi bitmask) ; k0b (images -> bf16 [b][row][col][ci16] imgT) ;
// kw/kw1 (weights -> bf16 MFMA-fragment order) ; k1_mfma (conv1+relu+pool ->
// bf16 pooledT [b][ph][pw][co]) ; k2_mfma (conv2+relu+PE -> f32 x2) ;
// k3 (roi max partials, LDS-shared x) ; k4 (merge 8 pos-partials).

typedef __attribute__((ext_vector_type(8))) short short8;   // MFMA bf16 A/B frag
typedef __attribute__((ext_vector_type(4))) float f32x4;    // MFMA C/D frag
typedef __attribute__((ext_vector_type(4))) unsigned short us4;
typedef unsigned short u16;

__device__ __forceinline__ u16 f2bf(float f) {  // RNE f32 -> bf16 bits
  unsigned u = __builtin_bit_cast(unsigned, f);
  return (u16)((u + 0x7fffu + ((u >> 16) & 1u)) >> 16);
}

__device__ __forceinline__ float fand(float x, unsigned m) {
  return __builtin_bit_cast(float, __builtin_bit_cast(unsigned, x) & m);
}

namespace {

// ---------------- k0: rois[:,:,::2,::2] -> per-position 32-bit object mask ----
// v2: thread handles TWO adjacent pooled-w positions via one uint4 load per o
// (words 4wp..4wp+3 contain both needed words 4wp and 4wp+2) -> every fetched
// line fully used (R5 version wasted half of each 16B).
__global__ __launch_bounds__(256) void k0_rmask(const unsigned* __restrict__ rois,
                                                unsigned* __restrict__ rmask) {
  const int lane = threadIdx.x & 63;
  unsigned ok = 1u;
#pragma unroll
  for (int i = 0; i < 4; ++i) {
    unsigned v = rois[lane * 4 + i];
    ok &= ((v <= 1u) || (v == 0x3f800000u)) ? 1u : 0u;
  }
  const bool isWord = (__all((int)ok) != 0);  // 4-byte elements
  const unsigned char* roisB = (const unsigned char*)rois;

  const int pi = blockIdx.x * 256 + threadIdx.x;  // pair index 0..32767
  const int b = pi >> 11;
  const int pp = pi & 2047;
  const int h = pp >> 5;    // pooled row
  const int wp = pp & 31;   // pooled-w pair: w = 2wp, 2wp+1
  const size_t base = (size_t)b * 32 * 16384 + (size_t)(2 * h) * 128 + 4 * wp;
  unsigned m0 = 0, m1 = 0;
#pragma unroll
  for (int o = 0; o < 32; ++o) {
    const size_t idx = base + (size_t)o * 16384;
    if (isWord) {
      const uint4 q = *(const uint4*)&rois[idx];
      m0 |= (unsigned)(q.x != 0u) << o;
      m1 |= (unsigned)(q.z != 0u) << o;
    } else {
      const unsigned q = *(const unsigned*)&roisB[idx];
      m0 |= (unsigned)((q & 0xffu) != 0u) << o;
      m1 |= (unsigned)((q & 0xff0000u) != 0u) << o;
    }
  }
  *(uint2*)&rmask[b * 4096 + h * 64 + wp * 2] = make_uint2(m0, m1);
}

// ---------------- k0b: images f32 [b][12][128][128] -> bf16 imgT [b][row][col][16] (ci pad->0)
__global__ __launch_bounds__(256) void k0b_imgT(const float* __restrict__ img,
                                                u16* __restrict__ imgT) {
  __shared__ alignas(16) u16 ST[2048];  // [col 0..127][cip 0..15]
  const int row = blockIdx.x, b = blockIdx.y;
  const int t = threadIdx.x;
#pragma unroll
  for (int i = 0; i < 2; ++i) {  // zero pads cip 12..15
    const int e = i * 256 + t;   // 0..511
    ST[(e >> 2) * 16 + 12 + (e & 3)] = 0;
  }
#pragma unroll
  for (int i = 0; i < 6; ++i) {  // 12 ci x 128 col
    const int e = i * 256 + t;   // 0..1535
    const int ci = e >> 7, col = e & 127;
    const float v = img[(((size_t)(b * 12 + ci)) << 14) + row * 128 + col];
    ST[col * 16 + ci] = f2bf(v);
  }
  __syncthreads();
  us4* dst = (us4*)(imgT + (((size_t)(b * 128 + row)) << 11));
#pragma unroll
  for (int i = 0; i < 2; ++i) {
    const int q = i * 256 + t;  // 0..511 us4 chunks
    dst[q] = *(const us4*)&ST[q * 4];
  }
}

// ---------------- kw: w2 f32 [co][64][3][3] -> bf16 A-fragments, K-order k=32ks+g*8+j,
// k -> (rc = k>>6, ci = k&63), src = w2[co*576 + ci*9 + rc]. idx=((cot*18+ks)*64+lane)*8+j
__global__ __launch_bounds__(256) void kw_prep(const float* __restrict__ w2,
                                               u16* __restrict__ Aw) {
  const int idx = blockIdx.x * 256 + threadIdx.x;  // 0..73727
  const int j = idx & 7;
  const int lane = (idx >> 3) & 63;
  const int t3 = idx >> 9;
  const int ks = t3 % 18, cot = t3 / 18;
  const int m = lane & 15, g = lane >> 4;
  const int co = cot * 16 + m;
  const int k = ks * 32 + g * 8 + j;
  const int rc = k >> 6, ci = k & 63;
  Aw[idx] = f2bf(w2[co * 576 + ci * 9 + rc]);
}

// ---------------- kw1: w1 f32 [co][12][3][3] -> bf16 A-frags, K padded 108->160.
// k=32ks+g*8+j -> (rc=k>>4, cip=k&15); pad (rc>=9 || cip>=12) -> 0.
__global__ __launch_bounds__(256) void kw1_prep(const float* __restrict__ w1,
                                                u16* __restrict__ Aw1) {
  const int idx = blockIdx.x * 256 + threadIdx.x;  // 0..10239
  const int j = idx & 7;
  const int lane = (idx >> 3) & 63;
  const int t3 = idx >> 9;           // cot*5 + ks
  const int ks = t3 % 5, cot = t3 / 5;
  const int m = lane & 15, g = lane >> 4;
  const int co = cot * 16 + m;
  const int k = ks * 32 + g * 8 + j;
  const int rc = k >> 4, cip = k & 15;
  const float v = (rc < 9 && cip < 12) ? w1[co * 108 + cip * 9 + rc] : 0.f;
  Aw1[idx] = f2bf(v);
}

// ---------------- k1: conv1 (MFMA) + bias + relu + pool -> pooledT bf16 [b][ph][pw][co]
__global__ __launch_bounds__(256) void k1_mfma(const u16* __restrict__ imgT,
                                               const u16* __restrict__ Aw1,
                                               const float* __restrict__ b1,
                                               u16* __restrict__ pooledT) {
  __shared__ alignas(16) u16 SIMG[8192];     // 16 KB
  __shared__ alignas(16) u16 PT[64 * 68];    // pooled [pw][co], pad-68 stride
  const int h2 = blockIdx.x, b = blockIdx.y;
  const int t = threadIdx.x, wv = t >> 6, l = t & 63;

#pragma unroll
  for (int i = 0; i < 4; ++i) {  // stage 4 rows x 4KB
    const int q = i * 256 + t;   // 16B chunk 0..1023
    const int sr = q >> 8, off = q & 255;
    const int irow = 2 * h2 - 1 + sr;
    short8 v = {0, 0, 0, 0, 0, 0, 0, 0};
    if ((unsigned)irow < 128u)
      v = *(const short8*)(imgT + (((size_t)(b * 128 + irow)) << 11) + off * 8);
    *(short8*)(SIMG + q * 8) = v;
  }
  __syncthreads();

  const int m16 = l & 15, g = l >> 4;
  const int colhalf = wv >> 1, cotbase = (wv & 1) * 2;
  f32x4 acc[2][8];
#pragma unroll
  for (int ct = 0; ct < 2; ++ct)
#pragma unroll
    for (int pt = 0; pt < 8; ++pt) acc[ct][pt] = (f32x4){0.f, 0.f, 0.f, 0.f};

  const u16* awb = Aw1 + (size_t)l * 8;
  const int cipb = (g & 1) * 16;  // byte offset of cip0 within 32B col-slot

#pragma unroll
  for (int ks = 0; ks < 5; ++ks) {
    short8 a0 = *(const short8*)(awb + (cotbase * 5 + ks) * 512);
    short8 a1 = *(const short8*)(awb + ((cotbase + 1) * 5 + ks) * 512);
    const bool pad = (ks == 4) && (g >= 2);  // k in [144,160): zero slots
    int rc = pad ? 0 : (2 * ks + (g >> 1));  // 0..8
    const int rr = (rc * 11) >> 5;           // rc/3
    const int cc = rc - rr * 3;              // rc%3
#pragma unroll
    for (int pt = 0; pt < 8; ++pt) {
      const int r01 = pt >> 2, ct2 = pt & 3;
      const int icol = colhalf * 64 + ct2 * 16 + m16 - 1 + cc;  // -1..128
      const bool ok = ((unsigned)icol < 128u) && !pad;
      const int ic = ok ? icol : 0;
      const int sr = r01 + rr;  // 0..3 (pad forces rr=0)
      short8 bv = *(const short8*)((const char*)SIMG + sr * 4096 + ic * 32 + cipb);
      if (!ok) bv = (short8){0, 0, 0, 0, 0, 0, 0, 0};
      acc[0][pt] = __builtin_amdgcn_mfma_f32_16x16x32_bf16(a0, bv, acc[0][pt], 0, 0, 0);
      acc[1][pt] = __builtin_amdgcn_mfma_f32_16x16x32_bf16(a1, bv, acc[1][pt], 0, 0, 0);
    }
  }

  // relu + 2x2 pool (rows in-lane, col pairs via shfl_xor) -> PT[pw][co]
#pragma unroll
  for (int ct = 0; ct < 2; ++ct) {
    const int cot = cotbase + ct;
#pragma unroll
    for (int r = 0; r < 4; ++r) {
      const int co = cot * 16 + g * 4 + r;
      const float bias = b1[co];
#pragma unroll
      for (int ct2 = 0; ct2 < 4; ++ct2) {
        float v0 = fmaxf(acc[ct][ct2][r] + bias, 0.f);
        float v1 = fmaxf(acc[ct][4 + ct2][r] + bias, 0.f);
        float vv = fmaxf(v0, v1);
        vv = fmaxf(vv, __shfl_xor(vv, 1, 64));
        if (!(m16 & 1)) {
          const int pw = colhalf * 32 + ct2 * 8 + (m16 >> 1);
          PT[pw * 68 + co] = f2bf(vv);
        }
      }
    }
  }
  __syncthreads();
  u16* dst = pooledT + (((size_t)(b * 64 + h2)) << 12);
#pragma unroll
  for (int i = 0; i < 4; ++i) {
    const int e = (i * 256 + t) * 4;
    const int pw = e >> 6, co = e & 63;
    *(us4*)(dst + e) = *(const us4*)&PT[pw * 68 + co];
  }
}

// ---------------- k2: conv2 (MFMA) + bias + relu + PE -> x2 f32 [b][co][h][w]
__global__ __launch_bounds__(256) void k2_mfma(const u16* __restrict__ pooledT,
                                               const u16* __restrict__ Aw,
                                               const float* __restrict__ b2,
                                               const float* __restrict__ dw,
                                               const float* __restrict__ db,
                                               float* __restrict__ x2) {
  __shared__ alignas(16) short8 SIN8[1536];  // 24 KB
  char* SB = (char*)SIN8;
  const int h = blockIdx.x, b = blockIdx.y;
  const int t = threadIdx.x, wv = t >> 6, l = t & 63;

#pragma unroll
  for (int i = 0; i < 6; ++i) {  // 24 chunks x 1KB
    const int chunk = i * 4 + wv;
    const int row = chunk >> 3;
    const int hin = h - 1 + row;
    short8 v = {0, 0, 0, 0, 0, 0, 0, 0};
    if ((unsigned)hin < 64u)
      v = *(const short8*)(pooledT + (((size_t)(b * 64 + hin)) << 12) +
                           ((chunk & 7) << 9) + l * 8);
    const int lin = chunk * 1024 + l * 16;
    *(short8*)(SB + (lin ^ (((lin >> 7) & 7) << 4))) = v;  // T2 XOR swizzle
  }
  __syncthreads();

  const int m16 = l & 15, g = l >> 4;
  const int kbyte = g * 16;
  f32x4 acc[2][4];
#pragma unroll
  for (int ct = 0; ct < 2; ++ct)
#pragma unroll
    for (int n = 0; n < 4; ++n) acc[ct][n] = (f32x4){0.f, 0.f, 0.f, 0.f};

  const u16* aw0 = Aw + (size_t)wv * 36 * 512 + l * 8;  // cot = 2wv

#pragma unroll
  for (int ks = 0; ks < 18; ++ks) {
    const int rc = ks >> 1, r = rc / 3, c = rc % 3;  // compile-time
    const int koff = r * 8192 + (ks & 1) * 64 + kbyte;
    short8 a0 = *(const short8*)(aw0 + ks * 512);
    short8 a1 = *(const short8*)(aw0 + (18 + ks) * 512);
    const int d = m16 + c - 1;  // -1..16
#pragma unroll
    for (int n = 0; n < 4; ++n) {
      const int icol = n * 16 + d;
      const bool ok = (unsigned)icol < 64u;
      const int ic = ok ? icol : (icol < 0 ? 0 : 63);
      int addr = koff + ic * 128;
      addr ^= (ic & 7) << 4;  // matching read-side swizzle
      short8 bv = *(const short8*)(SB + addr);
      if (!ok) bv = (short8){0, 0, 0, 0, 0, 0, 0, 0};
      acc[0][n] = __builtin_amdgcn_mfma_f32_16x16x32_bf16(a0, bv, acc[0][n], 0, 0, 0);
      acc[1][n] = __builtin_amdgcn_mfma_f32_16x16x32_bf16(a1, bv, acc[1][n], 0, 0, 0);
    }
  }

  // epilogue: relu(acc + b2) + pe ; pe = gy*(W0-W2) + gx*(W1-W3) + W2+W3+db
  const float inv63 = 1.f / 63.f;
  const float gy = (float)h * inv63;
#pragma unroll
  for (int ct = 0; ct < 2; ++ct) {
    const int cot = wv * 2 + ct;
#pragma unroll
    for (int r = 0; r < 4; ++r) {
      const int co = cot * 16 + g * 4 + r;
      const float bias = b2[co];
      const float W0 = dw[co * 4 + 0], W1 = dw[co * 4 + 1];
      const float W2 = dw[co * 4 + 2], W3 = dw[co * 4 + 3];
      const float pe0 = gy * (W0 - W2) + W2 + W3 + db[co];
      const float s13 = W1 - W3;
      float* orow = x2 + (((size_t)(b * 128 + co)) << 12) + h * 64;
#pragma unroll
      for (int n = 0; n < 4; ++n) {
        const int w = n * 16 + m16;
        orow[w] = fmaxf(acc[ct][n][r] + bias, 0.f) + pe0 + (float)w * inv63 * s13;
      }
    }
  }
}

// ---------------- k3: roi-masked spatial max -> partial[pq][b][o][c] ----------
// v5: block (cg, pq, b) = (8,8,16); stages [16 c][512 pos] f32 (stride 516 ->
// 2-way-free b128 reads) + mask[512] in LDS. lane = (o-group of 4, c-pair);
// waves split the 512 pos into 128 each. Per-thread state = 8 accums ->
// guaranteed VGPR-resident (R4/R5 lesson: >=64 accums -> AGPR ping-pong, 3x
// op inflation). Per 4-pos iter: 3 ds_read_b128 + 16 bfe + 32 and + 16 max3
// = 2.0 VALU ops/elem. In-block cross-wave merge reuses LDS; k4 merges pq.
__global__ __launch_bounds__(256) void k3_roi(const float* __restrict__ x2,
                                              const unsigned* __restrict__ rmask,
                                              float* __restrict__ partial) {
  __shared__ alignas(16) char LB[35072];
  float(*XS)[516] = (float(*)[516])LB;          // 16 rows x 516 f32 (33024 B)
  unsigned* MS = (unsigned*)(LB + 33024);       // 512 mask words
  const int cg = blockIdx.x, pq = blockIdx.y, b = blockIdx.z;
  const int t = threadIdx.x, wv = t >> 6, lane = t & 63;
  const int p0 = pq * 512;

#pragma unroll
  for (int i = 0; i < 8; ++i) {  // stage 16 c x 512 pos (2048 float4)
    const int f4id = i * 256 + t;
    const int c = f4id >> 7, p4 = (f4id & 127) * 4;
    const float4 v = *(const float4*)&x2[(((size_t)(b * 128 + cg * 16 + c)) << 12) + p0 + p4];
    *(float4*)&XS[c][p4] = v;
  }
  if (t < 128) *(uint4*)&MS[t * 4] = *(const uint4*)&rmask[b * 4096 + p0 + t * 4];
  __syncthreads();

  const int ob = (lane >> 3) * 4;  // base o of this thread's 4 objects
  const int cp = lane & 7;         // c-pair
  const float* r0 = XS[cp * 2];
  const float* r1 = XS[cp * 2 + 1];
  const int ps = wv * 128;         // wave's pos subrange

  float a[4][2];
#pragma unroll
  for (int r = 0; r < 4; ++r) { a[r][0] = -3.4e38f; a[r][1] = -3.4e38f; }

  for (int p = ps; p < ps + 128; p += 4) {
    const uint4 mw = *(const uint4*)&MS[p];      // uniform addr -> broadcast
    const float4 xa = *(const float4*)&r0[p];
    const float4 xb = *(const float4*)&r1[p];
#pragma unroll
    for (int r = 0; r < 4; ++r) {                // unrolled -> static a[][] idx
      const int o = ob + r;
      const unsigned m0 = (unsigned)((int)(mw.x << (31 - o)) >> 31);  // bfe
      const unsigned m1 = (unsigned)((int)(mw.y << (31 - o)) >> 31);
      const unsigned m2 = (unsigned)((int)(mw.z << (31 - o)) >> 31);
      const unsigned m3 = (unsigned)((int)(mw.w << (31 - o)) >> 31);
      a[r][0] = fmaxf(fmaxf(a[r][0], fand(xa.x, m0)), fand(xa.y, m1));  // max3
      a[r][0] = fmaxf(fmaxf(a[r][0], fand(xa.z, m2)), fand(xa.w, m3));
      a[r][1] = fmaxf(fmaxf(a[r][1], fand(xb.x, m0)), fand(xb.y, m1));
      a[r][1] = fmaxf(fmaxf(a[r][1], fand(xb.z, m2)), fand(xb.w, m3));
    }
  }

  __syncthreads();                 // XS/MS dead; reuse LB for reduction
  float* RED = (float*)LB;         // [4 wv][64 lane][8 slot]
#pragma unroll
  for (int r = 0; r < 4; ++r) {
    RED[(wv * 64 + lane) * 8 + r * 2 + 0] = a[r][0];
    RED[(wv * 64 + lane) * 8 + r * 2 + 1] = a[r][1];
  }
  __syncthreads();
#pragma unroll
  for (int u0 = 0; u0 < 2; ++u0) {  // 512 outputs, 2 per thread
    const int u = u0 * 256 + t;
    const int o = u >> 4, cl = u & 15;
    const int ln = (o >> 2) * 8 + (cl >> 1);
    const int sl = (o & 3) * 2 + (cl & 1);
    float v = fmaxf(fmaxf(RED[(0 * 64 + ln) * 8 + sl], RED[(1 * 64 + ln) * 8 + sl]),
                    fmaxf(RED[(2 * 64 + ln) * 8 + sl], RED[(3 * 64 + ln) * 8 + sl]));
    partial[(size_t)pq * 65536 + ((size_t)b * 32 + o) * 128 + cg * 16 + cl] = v;
  }
}

// ---------------- k4: out[idx] = max over 8 pos-partials -----------------------
__global__ __launch_bounds__(256) void k4_merge(const float* __restrict__ partial,
                                                float* __restrict__ out) {
  const int idx = blockIdx.x * 256 + threadIdx.x;  // 0..65535 = [b][o][c]
  float v = partial[idx];
#pragma unroll
  for (int q = 1; q < 8; ++q) v = fmaxf(v, partial[q * 65536 + idx]);
  out[idx] = v;
}

}  // namespace

extern "C" void kernel_launch(void* const* d_in, const int* in_sizes, int n_in,
                              void* d_out, int out_size, void* d_ws, size_t ws_size,
                              hipStream_t stream) {
  const float* images = (const float*)d_in[0];
  const unsigned* rois = (const unsigned*)d_in[1];
  const float* w1 = (const float*)d_in[2];
  const float* b1 = (const float*)d_in[3];
  const float* w2 = (const float*)d_in[4];
  const float* b2 = (const float*)d_in[5];
  const float* dw = (const float*)d_in[6];
  const float* db = (const float*)d_in[7];
  float* out = (float*)d_out;

  char* ws = (char*)d_ws;
  // rmask 256KB @0 ; pooledT 8MB @0x40000 (dead after k2 -> partial reuses it);
  // Aw2 144KB @0x840000 ; Aw1 20KB @0x864000 ; imgT 8MB @0x900000 (dead after
  // k1) ; x2 32MB @0x900000 (overlaps imgT) ; partial 2MB @0x40000.
  unsigned* rmask = (unsigned*)(ws);
  u16* pooledT = (u16*)(ws + 0x40000);
  u16* Aw2 = (u16*)(ws + 0x840000);
  u16* Aw1 = (u16*)(ws + 0x864000);
  u16* imgT = (u16*)(ws + 0x900000);
  float* x2 = (float*)(ws + 0x900000);
  float* partial = (float*)(ws + 0x40000);

  hipLaunchKernelGGL(k0_rmask, dim3(128), dim3(256), 0, stream, rois, rmask);
  hipLaunchKernelGGL(k0b_imgT, dim3(128, 16), dim3(256), 0, stream, images, imgT);
  hipLaunchKernelGGL(kw_prep, dim3(288), dim3(256), 0, stream, w2, Aw2);
  hipLaunchKernelGGL(kw1_prep, dim3(40), dim3(256), 0, stream, w1, Aw1);
  hipLaunchKernelGGL(k1_mfma, dim3(64, 16), dim3(256), 0, stream, imgT, Aw1, b1, pooledT);
  hipLaunchKernelGGL(k2_mfma, dim3(64, 16), dim3(256), 0, stream, pooledT, Aw2, b2, dw, db, x2);
  hipLaunchKernelGGL(k3_roi, dim3(8, 8, 16), dim3(256), 0, stream, x2, rmask, partial);
  hipLaunchKernelGGL(k4_merge, dim3(256), dim3(256), 0, stream, partial, out);
}

// Round 7
// 72.641 us; speedup vs baseline: 1.7467x; 1.1466x over previous
//
#include <hip/hip_runtime.h>

// B=16, 12 in-ch, 128x128 imgs; conv1->64ch +pool -> 64x64; conv2->128ch (+PE);
// roi max -> out (16,32,128) f32.
//
// Pipeline: kio (roi bitmask + images->bf16 imgT) ; kprep (w1,w2 -> MFMA frag
// order) ; k1_mfma (conv1+relu+pool -> bf16 pooledT) ; k2_mfma (conv2+relu+PE
// -> bf16 x2b) ; k3_roi (masked max in mapped-u16 packed domain -> partial) ;
// k4_merge (merge 8 pos-partials, unmap -> f32 out).

typedef __attribute__((ext_vector_type(8))) short short8;   // MFMA bf16 A/B frag
typedef __attribute__((ext_vector_type(4))) float f32x4;    // MFMA C/D frag
typedef __attribute__((ext_vector_type(4))) unsigned short us4;
typedef __attribute__((ext_vector_type(2))) unsigned short u16x2;
typedef unsigned short u16;
typedef unsigned int u32;

__device__ __forceinline__ u16 f2bf(float f) {  // RNE f32 -> bf16 bits
  u32 u = __builtin_bit_cast(u32, f);
  return (u16)((u + 0x7fffu + ((u >> 16) & 1u)) >> 16);
}

// packed unsigned 16-bit max (v_pk_max_u16)
__device__ __forceinline__ u32 pkmaxu(u32 a, u32 b) {
  u16x2 x = __builtin_bit_cast(u16x2, a), y = __builtin_bit_cast(u16x2, b);
  return __builtin_bit_cast(u32, __builtin_elementwise_max(x, y));
}
// monotone map bf16 -> u16 (unsigned order == float order), 2 at a time
__device__ __forceinline__ u32 map2(u32 v) {
  u32 flip = ((v & 0x80008000u) >> 15) * 0xFFFFu;  // 0xFFFF per negative half
  return v ^ (flip | 0x80008000u);
}
__device__ __forceinline__ float unmap1(u32 m) {  // mapped u16 -> f32
  u32 b = m ^ ((m & 0x8000u) ? 0x8000u : 0xFFFFu);
  return __builtin_bit_cast(float, b << 16);
}
__device__ __forceinline__ float fand(float x, u32 m) {
  return __builtin_bit_cast(float, __builtin_bit_cast(u32, x) & m);
}

namespace {

// ---------------- kio: [bx<2048] images -> bf16 imgT [b][row][col][ci16]
//                  [bx>=2048] rois[:,:,::2,::2] -> 32-bit object mask --------
__global__ __launch_bounds__(256) void kio(const float* __restrict__ img,
                                           u16* __restrict__ imgT,
                                           const unsigned* __restrict__ rois,
                                           unsigned* __restrict__ rmask) {
  __shared__ alignas(16) u16 ST[2048];  // [col 0..127][cip 0..15]
  const int bx = blockIdx.x;
  const int t = threadIdx.x;
  if (bx < 2048) {  // --- imgT conversion (was k0b) ---
    const int row = bx & 127, b = bx >> 7;
#pragma unroll
    for (int i = 0; i < 2; ++i) {  // zero pads cip 12..15
      const int e = i * 256 + t;
      ST[(e >> 2) * 16 + 12 + (e & 3)] = 0;
    }
#pragma unroll
    for (int i = 0; i < 6; ++i) {  // 12 ci x 128 col
      const int e = i * 256 + t;
      const int ci = e >> 7, col = e & 127;
      const float v = img[(((size_t)(b * 12 + ci)) << 14) + row * 128 + col];
      ST[col * 16 + ci] = f2bf(v);
    }
    __syncthreads();
    us4* dst = (us4*)(imgT + (((size_t)(b * 128 + row)) << 11));
#pragma unroll
    for (int i = 0; i < 2; ++i) {
      const int q = i * 256 + t;
      dst[q] = *(const us4*)&ST[q * 4];
    }
  } else {  // --- rmask (was k0 v2): 2 pooled-w per thread, full-line use ---
    const int lane = t & 63;
    u32 ok = 1u;
#pragma unroll
    for (int i = 0; i < 4; ++i) {
      u32 v = rois[lane * 4 + i];
      ok &= ((v <= 1u) || (v == 0x3f800000u)) ? 1u : 0u;
    }
    const bool isWord = (__all((int)ok) != 0);
    const unsigned char* roisB = (const unsigned char*)rois;
    const int pi = (bx - 2048) * 256 + t;  // 0..32767
    const int b = pi >> 11;
    const int pp = pi & 2047;
    const int h = pp >> 5;
    const int wp = pp & 31;
    const size_t base = (size_t)b * 32 * 16384 + (size_t)(2 * h) * 128 + 4 * wp;
    u32 m0 = 0, m1 = 0;
#pragma unroll
    for (int o = 0; o < 32; ++o) {
      const size_t idx = base + (size_t)o * 16384;
      if (isWord) {
        const uint4 q = *(const uint4*)&rois[idx];
        m0 |= (u32)(q.x != 0u) << o;
        m1 |= (u32)(q.z != 0u) << o;
      } else {
        const u32 q = *(const u32*)&roisB[idx];
        m0 |= (u32)((q & 0xffu) != 0u) << o;
        m1 |= (u32)((q & 0xff0000u) != 0u) << o;
      }
    }
    *(uint2*)&rmask[b * 4096 + h * 64 + wp * 2] = make_uint2(m0, m1);
  }
}

// ---------------- kprep: [bx<288] w2 -> Aw2 frags ; [bx>=288] w1 -> Aw1 ------
__global__ __launch_bounds__(256) void kprep(const float* __restrict__ w2,
                                             u16* __restrict__ Aw,
                                             const float* __restrict__ w1,
                                             u16* __restrict__ Aw1) {
  const int bx = blockIdx.x;
  if (bx < 288) {  // k = 32ks+g*8+j -> (rc=k>>6, ci=k&63)
    const int idx = bx * 256 + threadIdx.x;  // 0..73727
    const int j = idx & 7;
    const int lane = (idx >> 3) & 63;
    const int t3 = idx >> 9;
    const int ks = t3 % 18, cot = t3 / 18;
    const int m = lane & 15, g = lane >> 4;
    const int co = cot * 16 + m;
    const int k = ks * 32 + g * 8 + j;
    const int rc = k >> 6, ci = k & 63;
    Aw[idx] = f2bf(w2[co * 576 + ci * 9 + rc]);
  } else {  // K padded 108->160: k -> (rc=k>>4, cip=k&15)
    const int idx = (bx - 288) * 256 + threadIdx.x;  // 0..10239
    const int j = idx & 7;
    const int lane = (idx >> 3) & 63;
    const int t3 = idx >> 9;
    const int ks = t3 % 5, cot = t3 / 5;
    const int m = lane & 15, g = lane >> 4;
    const int co = cot * 16 + m;
    const int k = ks * 32 + g * 8 + j;
    const int rc = k >> 4, cip = k & 15;
    const float v = (rc < 9 && cip < 12) ? w1[co * 108 + cip * 9 + rc] : 0.f;
    Aw1[idx] = f2bf(v);
  }
}

// ---------------- k1: conv1 (MFMA) + bias + relu + pool -> pooledT bf16 ------
// Diet: per-ks base addr + imm-offset reads; edge-only zeroing; SIMG gets a
// ((ic>>2)&1)<<4 XOR swizzle on write AND read -> 8-way bank conflict -> 2-way.
__global__ __launch_bounds__(256) void k1_mfma(const u16* __restrict__ imgT,
                                               const u16* __restrict__ Aw1,
                                               const float* __restrict__ b1,
                                               u16* __restrict__ pooledT) {
  __shared__ alignas(16) u16 SIMG[8192];   // 16 KB, swizzled
  __shared__ alignas(16) u16 PT[64 * 68];  // pooled [pw][co]
  const int h2 = blockIdx.x, b = blockIdx.y;
  const int t = threadIdx.x, wv = t >> 6, l = t & 63;

#pragma unroll
  for (int i = 0; i < 4; ++i) {  // stage 4 rows x 4KB (swizzled store)
    const int q = i * 256 + t;
    const int sr = q >> 8, off = q & 255;
    const int irow = 2 * h2 - 1 + sr;
    short8 v = {0, 0, 0, 0, 0, 0, 0, 0};
    if ((unsigned)irow < 128u)
      v = *(const short8*)(imgT + (((size_t)(b * 128 + irow)) << 11) + off * 8);
    *(short8*)((char*)SIMG + ((q * 16) ^ (((q >> 3) & 1) << 4))) = v;
  }
  __syncthreads();

  const int m16 = l & 15, g = l >> 4;
  const int colhalf = wv >> 1, cotbase = (wv & 1) * 2;
  const int cipb = (g & 1) * 16;
  f32x4 acc[2][8];
#pragma unroll
  for (int ct = 0; ct < 2; ++ct)
#pragma unroll
    for (int pt = 0; pt < 8; ++pt) acc[ct][pt] = (f32x4){0.f, 0.f, 0.f, 0.f};

  const u16* awb = Aw1 + (size_t)l * 8;
  const short8 z8 = {0, 0, 0, 0, 0, 0, 0, 0};

#pragma unroll
  for (int ks = 0; ks < 5; ++ks) {
    short8 a0 = *(const short8*)(awb + (cotbase * 5 + ks) * 512);
    short8 a1 = *(const short8*)(awb + ((cotbase + 1) * 5 + ks) * 512);
    const bool pz = (ks == 4) && (g >= 2);   // zero-padded K slots
    const int rc = pz ? 0 : (2 * ks + (g >> 1));
    const int rr = (rc * 11) >> 5;           // rc/3
    const int cc = rc - rr * 3;              // rc%3
    const int d = m16 - 1 + cc;              // -1..16
    const int sb = (d < 0) ? 1 : ((d >> 2) & 1);
    const int base = rr * 4096 + d * 32 + colhalf * 2048 + (cipb ^ (sb << 4));
    const bool killLo = (cc == 0) && (m16 == 0) && (colhalf == 0);   // pt 0,4
    const bool killHi = (cc == 2) && (m16 == 15) && (colhalf == 1);  // pt 3,7
#pragma unroll
    for (int pt = 0; pt < 8; ++pt) {
      const int r01 = pt >> 2, ct2 = pt & 3;
      short8 bv = *(const short8*)((const char*)SIMG + base + r01 * 4096 + ct2 * 512);
      bool kill = pz;
      if (ct2 == 0) kill = kill || killLo;
      if (ct2 == 3) kill = kill || killHi;
      if (kill) bv = z8;
      acc[0][pt] = __builtin_amdgcn_mfma_f32_16x16x32_bf16(a0, bv, acc[0][pt], 0, 0, 0);
      acc[1][pt] = __builtin_amdgcn_mfma_f32_16x16x32_bf16(a1, bv, acc[1][pt], 0, 0, 0);
    }
  }

  // relu + 2x2 pool -> PT[pw][co]
#pragma unroll
  for (int ct = 0; ct < 2; ++ct) {
    const int cot = cotbase + ct;
#pragma unroll
    for (int r = 0; r < 4; ++r) {
      const int co = cot * 16 + g * 4 + r;
      const float bias = b1[co];
#pragma unroll
      for (int ct2 = 0; ct2 < 4; ++ct2) {
        float v0 = fmaxf(acc[ct][ct2][r] + bias, 0.f);
        float v1 = fmaxf(acc[ct][4 + ct2][r] + bias, 0.f);
        float vv = fmaxf(v0, v1);
        vv = fmaxf(vv, __shfl_xor(vv, 1, 64));
        if (!(m16 & 1)) {
          const int pw = colhalf * 32 + ct2 * 8 + (m16 >> 1);
          PT[pw * 68 + co] = f2bf(vv);
        }
      }
    }
  }
  __syncthreads();
  u16* dst = pooledT + (((size_t)(b * 64 + h2)) << 12);
#pragma unroll
  for (int i = 0; i < 4; ++i) {
    const int e = (i * 256 + t) * 4;
    const int pw = e >> 6, co = e & 63;
    *(us4*)(dst + e) = *(const us4*)&PT[pw * 68 + co];
  }
}

// ---------------- k2: conv2 (MFMA) + bias + relu + PE -> x2b bf16 [b][co][pos]
// Diet: per-ks base + imm-offset ds_reads (swizzle XOR commutes with +2048n);
// edge zeroing only at (c==0,n==0)/(c==2,n==3). Output bf16 (halves traffic).
__global__ __launch_bounds__(256) void k2_mfma(const u16* __restrict__ pooledT,
                                               const u16* __restrict__ Aw,
                                               const float* __restrict__ b2,
                                               const float* __restrict__ dw,
                                               const float* __restrict__ db,
                                               u16* __restrict__ x2b) {
  __shared__ alignas(16) short8 SIN8[1536];  // 24 KB
  char* SB = (char*)SIN8;
  const int h = blockIdx.x, b = blockIdx.y;
  const int t = threadIdx.x, wv = t >> 6, l = t & 63;

#pragma unroll
  for (int i = 0; i < 6; ++i) {  // stage rows h-1..h+1, T2 XOR swizzle
    const int chunk = i * 4 + wv;
    const int row = chunk >> 3;
    const int hin = h - 1 + row;
    short8 v = {0, 0, 0, 0, 0, 0, 0, 0};
    if ((unsigned)hin < 64u)
      v = *(const short8*)(pooledT + (((size_t)(b * 64 + hin)) << 12) +
                           ((chunk & 7) << 9) + l * 8);
    const int lin = chunk * 1024 + l * 16;
    *(short8*)(SB + (lin ^ (((lin >> 7) & 7) << 4))) = v;
  }
  __syncthreads();

  const int m16 = l & 15, g = l >> 4;
  const int kbyte = g * 16;
  f32x4 acc[2][4];
#pragma unroll
  for (int ct = 0; ct < 2; ++ct)
#pragma unroll
    for (int n = 0; n < 4; ++n) acc[ct][n] = (f32x4){0.f, 0.f, 0.f, 0.f};

  const u16* aw0 = Aw + (size_t)wv * 36 * 512 + l * 8;  // cot = 2wv
  const short8 z8 = {0, 0, 0, 0, 0, 0, 0, 0};

#pragma unroll
  for (int ks = 0; ks < 18; ++ks) {
    const int rc = ks >> 1, r = rc / 3, c = rc % 3;  // compile-time
    const int koff = r * 8192 + (ks & 1) * 64 + kbyte;
    short8 a0 = *(const short8*)(aw0 + ks * 512);
    short8 a1 = *(const short8*)(aw0 + (18 + ks) * 512);
    const int d = m16 + c - 1;                      // -1..16
    const int base = (koff + d * 128) ^ ((d & 7) << 4);
    const bool edgeLo = (c == 0) && (m16 == 0);     // n==0 OOB
    const bool edgeHi = (c == 2) && (m16 == 15);    // n==3 OOB
#pragma unroll
    for (int n = 0; n < 4; ++n) {
      short8 bv = *(const short8*)(SB + base + n * 2048);
      if (c == 0 && n == 0) { if (edgeLo) bv = z8; }
      if (c == 2 && n == 3) { if (edgeHi) bv = z8; }
      acc[0][n] = __builtin_amdgcn_mfma_f32_16x16x32_bf16(a0, bv, acc[0][n], 0, 0, 0);
      acc[1][n] = __builtin_amdgcn_mfma_f32_16x16x32_bf16(a1, bv, acc[1][n], 0, 0, 0);
    }
  }

  // epilogue: relu(acc + b2) + pe -> bf16
  const float inv63 = 1.f / 63.f;
  const float gy = (float)h * inv63;
#pragma unroll
  for (int ct = 0; ct < 2; ++ct) {
    const int cot = wv * 2 + ct;
#pragma unroll
    for (int r = 0; r < 4; ++r) {
      const int co = cot * 16 + g * 4 + r;
      const float bias = b2[co];
      const float W0 = dw[co * 4 + 0], W1 = dw[co * 4 + 1];
      const float W2 = dw[co * 4 + 2], W3 = dw[co * 4 + 3];
      const float pe0 = gy * (W0 - W2) + W2 + W3 + db[co];
      const float s13 = W1 - W3;
      u16* orow = x2b + (((size_t)(b * 128 + co)) << 12) + h * 64;
#pragma unroll
      for (int n = 0; n < 4; ++n) {
        const int w = n * 16 + m16;
        orow[w] = f2bf(fmaxf(acc[ct][n][r] + bias, 0.f) + pe0 + (float)w * inv63 * s13);
      }
    }
  }
}

// ---------------- k3: masked spatial max in packed mapped-u16 domain ---------
// block (cg,pq,b)=(8,8,16). Stage [16 c][512 pos] bf16 -> mapped u16 (monotone
// map: unsigned max == float max), stride 260 u32 (2-way-free banks) + 512
// masks. lane=(og*8+cu): 4 o x 2 c per thread = 8 u32 accums (VGPR-safe).
// Per (o,pos-pair): 2 bfe + bfi-combine; per c: bfi(select map(+0)=0x8000 for
// masked-out, == reference x*r) + v_pk_max_u16. Waves split 512 pos.
__global__ __launch_bounds__(256) void k3_roi(const u16* __restrict__ x2b,
                                              const unsigned* __restrict__ rmask,
                                              u32* __restrict__ partial) {
  __shared__ alignas(16) char LB[18688];
  u32* XSU = (u32*)LB;                    // [16 c][260] (256 used)
  u32* MS = (u32*)(LB + 16640);           // 512 mask words
  const int cg = blockIdx.x, pq = blockIdx.y, b = blockIdx.z;
  const int t = threadIdx.x, wv = t >> 6, lane = t & 63;
  const int p0 = pq * 512;

#pragma unroll
  for (int i = 0; i < 4; ++i) {  // stage+map 16 c x 512 pos (1024 uint4)
    const int f4 = i * 256 + t;
    const int c = f4 >> 6, cidx = f4 & 63;
    uint4 v = *(const uint4*)&x2b[(((size_t)(b * 128 + cg * 16 + c)) << 12) + p0 + cidx * 8];
    v.x = map2(v.x); v.y = map2(v.y); v.z = map2(v.z); v.w = map2(v.w);
    *(uint4*)&XSU[c * 260 + cidx * 4] = v;
  }
  if (t < 128) *(uint4*)&MS[t * 4] = *(const uint4*)&rmask[b * 4096 + p0 + t * 4];
  __syncthreads();

  const int og = lane >> 3, cu = lane & 7;
  const u32* r0 = XSU + (2 * cu) * 260;
  const u32* r1 = XSU + (2 * cu + 1) * 260;
  const int ps = wv * 128;

  u32 a[4][2];  // [o-sub r][c-sub j], packed (even,odd) running max; 0 = -inf
#pragma unroll
  for (int r = 0; r < 4; ++r) { a[r][0] = 0u; a[r][1] = 0u; }

  for (int pi = 0; pi < 32; ++pi) {
    const int p = ps + pi * 4;
    const uint4 mw = *(const uint4*)&MS[p];     // uniform -> broadcast
    const uint2 xa = *(const uint2*)&r0[p >> 1];
    const uint2 xb = *(const uint2*)&r1[p >> 1];
#pragma unroll
    for (int r = 0; r < 4; ++r) {
      const int o = og * 4 + r;
      u32 t0 = (u32)((int)(mw.x << (31 - o)) >> 31);
      u32 t1 = (u32)((int)(mw.y << (31 - o)) >> 31);
      u32 pm = (t0 & 0xFFFFu) | (t1 & 0xFFFF0000u);         // v_bfi
      a[r][0] = pkmaxu(a[r][0], (xa.x & pm) | (0x80008000u & ~pm));
      a[r][1] = pkmaxu(a[r][1], (xb.x & pm) | (0x80008000u & ~pm));
      t0 = (u32)((int)(mw.z << (31 - o)) >> 31);
      t1 = (u32)((int)(mw.w << (31 - o)) >> 31);
      pm = (t0 & 0xFFFFu) | (t1 & 0xFFFF0000u);
      a[r][0] = pkmaxu(a[r][0], (xa.y & pm) | (0x80008000u & ~pm));
      a[r][1] = pkmaxu(a[r][1], (xb.y & pm) | (0x80008000u & ~pm));
    }
  }

  __syncthreads();               // XSU/MS dead; reuse LB for reduction
  u32* RED = (u32*)LB;           // [4 wv][64 lane][8 slot]
#pragma unroll
  for (int r = 0; r < 4; ++r) {  // static indices only (rule #20)
    RED[(wv * 64 + lane) * 8 + r * 2 + 0] = a[r][0];
    RED[(wv * 64 + lane) * 8 + r * 2 + 1] = a[r][1];
  }
  __syncthreads();
  // 256 threads: one (o, c-pair) each; merge 4 waves, fold pos halves
  {
    const int o = t >> 3, clp = t & 7;
    const int sl = (o >> 2) * 8 + clp;
    const int s0 = (o & 3) * 2;
    u32 m0 = 0u, m1 = 0u;
#pragma unroll
    for (int w = 0; w < 4; ++w) {
      const uint2 q = *(const uint2*)&RED[(w * 64 + sl) * 8 + s0];
      m0 = pkmaxu(m0, q.x);
      m1 = pkmaxu(m1, q.y);
    }
    u32 f0l = m0 & 0xFFFFu, f0h = m0 >> 16;
    u32 f1l = m1 & 0xFFFFu, f1h = m1 >> 16;
    const u32 f0 = f0l > f0h ? f0l : f0h;
    const u32 f1 = f1l > f1h ? f1l : f1h;
    partial[(size_t)pq * 32768 + ((size_t)b * 32 + o) * 64 + cg * 8 + clp] =
        f0 | (f1 << 16);
  }
}

// ---------------- k4: merge 8 pq-partials (packed), unmap -> f32 out ---------
__global__ __launch_bounds__(256) void k4_merge(const u32* __restrict__ partial,
                                                float* __restrict__ out) {
  const int idx = blockIdx.x * 256 + threadIdx.x;  // 0..32767 u32s
  u32 v = partial[idx];
#pragma unroll
  for (int q = 1; q < 8; ++q) v = pkmaxu(v, partial[q * 32768 + idx]);
  float2 o2;
  o2.x = unmap1(v & 0xFFFFu);
  o2.y = unmap1(v >> 16);
  *(float2*)&out[idx * 2] = o2;
}

}  // namespace

extern "C" void kernel_launch(void* const* d_in, const int* in_sizes, int n_in,
                              void* d_out, int out_size, void* d_ws, size_t ws_size,
                              hipStream_t stream) {
  const float* images = (const float*)d_in[0];
  const unsigned* rois = (const unsigned*)d_in[1];
  const float* w1 = (const float*)d_in[2];
  const float* b1 = (const float*)d_in[3];
  const float* w2 = (const float*)d_in[4];
  const float* b2 = (const float*)d_in[5];
  const float* dw = (const float*)d_in[6];
  const float* db = (const float*)d_in[7];
  float* out = (float*)d_out;

  char* ws = (char*)d_ws;
  // rmask 256KB @0 ; pooledT 8MB @0x40000 (dead after k2; partial 1MB reuses);
  // Aw2 144KB @0x840000 ; Aw1 20KB @0x864000 ; imgT 8MB @0x900000 (dead after
  // k1) ; x2b bf16 16MB @0x900000 (overlaps imgT, written by k2).
  unsigned* rmask = (unsigned*)(ws);
  u16* pooledT = (u16*)(ws + 0x40000);
  u16* Aw2 = (u16*)(ws + 0x840000);
  u16* Aw1 = (u16*)(ws + 0x864000);
  u16* imgT = (u16*)(ws + 0x900000);
  u16* x2b = (u16*)(ws + 0x900000);
  u32* partial = (u32*)(ws + 0x40000);

  hipLaunchKernelGGL(kio, dim3(2176), dim3(256), 0, stream, images, imgT, rois, rmask);
  hipLaunchKernelGGL(kprep, dim3(328), dim3(256), 0, stream, w2, Aw2, w1, Aw1);
  hipLaunchKernelGGL(k1_mfma, dim3(64, 16), dim3(256), 0, stream, imgT, Aw1, b1, pooledT);
  hipLaunchKernelGGL(k2_mfma, dim3(64, 16), dim3(256), 0, stream, pooledT, Aw2, b2, dw, db, x2b);
  hipLaunchKernelGGL(k3_roi, dim3(8, 8, 16), dim3(256), 0, stream, x2b, rmask, partial);
  hipLaunchKernelGGL(k4_merge, dim3(128), dim3(256), 0, stream, partial, out);
}